// Round 2
// baseline (1159.935 us; speedup 1.0000x reference)
//
#include <hip/hip_runtime.h>
#include <hip/hip_bf16.h>

#define S_LEN 2048
#define HID   4096
#define NH    32
#define HD    128
#define KD    4096

typedef __attribute__((ext_vector_type(4))) float f32x4;
typedef __attribute__((ext_vector_type(8))) short s16x8;
typedef __attribute__((ext_vector_type(4))) short s16x4;

__device__ inline short f2bf(float f) {
  union { float f; unsigned u; } v; v.f = f;
  return (short)((v.u + 0x7fffu + ((v.u >> 16) & 1u)) >> 16);
}
__device__ inline float bf2f(short s) {
  union { unsigned u; float f; } v; v.u = ((unsigned)(unsigned short)s) << 16;
  return v.f;
}

// ---------------- GEMM: C[M x N] = A[M x KD](f32) * B[KD x N](f32) ----------------
// EPI 0: + bias, write bf16 scattered to Q/K/V head-major [NH][S][HD]
// EPI 1: write f32 to Cout[M x N]
template<int EPI>
__global__ __launch_bounds__(256)
void gemm_kernel(const float* __restrict__ A, const float* __restrict__ B,
                 const float* __restrict__ bias, const int N,
                 short* __restrict__ Qb, short* __restrict__ Kb, short* __restrict__ Vb,
                 float* __restrict__ Cout)
{
  __shared__ short As[128][40];   // [m][k], pad to 40 for bank spread
  __shared__ short Bs[128][40];   // [n][k] (transposed at staging)
  const int m0 = blockIdx.x * 128;
  const int nb = blockIdx.y * 128;
  const int t  = threadIdx.x;
  const int w = t >> 6, lane = t & 63, c = lane & 15, g = lane >> 4;
  const int wm = (w >> 1) * 64, wn = (w & 1) * 64;

  f32x4 acc[4][4];
#pragma unroll
  for (int i = 0; i < 4; i++)
#pragma unroll
    for (int j = 0; j < 4; j++) acc[i][j] = (f32x4){0.f, 0.f, 0.f, 0.f};

  const int ar = t >> 3;          // 0..31  (A stage: row group)
  const int ac = (t & 7) * 4;     // 0..28  (A stage: k offset)
  const int bn = t & 127;         // B stage: n
  const int bkq = (t >> 7) * 16;  // B stage: k half

  for (int k0 = 0; k0 < KD; k0 += 32) {
    // ---- stage A (128x32 f32 -> bf16, coalesced float4 reads) ----
#pragma unroll
    for (int rr = 0; rr < 4; rr++) {
      const int row = rr * 32 + ar;
      f32x4 v = *(const f32x4*)(A + (size_t)(m0 + row) * KD + k0 + ac);
      s16x4 pk;
      pk[0] = f2bf(v[0]); pk[1] = f2bf(v[1]); pk[2] = f2bf(v[2]); pk[3] = f2bf(v[3]);
      *(s16x4*)&As[row][ac] = pk;
    }
    // ---- stage B transposed (32x128 f32 -> Bs[n][k] bf16); dword reads coalesced over n ----
    const float* pB = B + (size_t)(k0 + bkq) * N + nb + bn;
    s16x8 b0, b1;
#pragma unroll
    for (int i = 0; i < 8; i++) b0[i] = f2bf(pB[(size_t)i * N]);
#pragma unroll
    for (int i = 0; i < 8; i++) b1[i] = f2bf(pB[(size_t)(i + 8) * N]);
    *(s16x8*)&Bs[bn][bkq]     = b0;
    *(s16x8*)&Bs[bn][bkq + 8] = b1;
    __syncthreads();
    // ---- compute ----
    s16x8 af[4], bfr[4];
#pragma unroll
    for (int i = 0; i < 4; i++) af[i]  = *(const s16x8*)&As[wm + i * 16 + c][g * 8];
#pragma unroll
    for (int i = 0; i < 4; i++) bfr[i] = *(const s16x8*)&Bs[wn + i * 16 + c][g * 8];
#pragma unroll
    for (int mi = 0; mi < 4; mi++)
#pragma unroll
      for (int ni = 0; ni < 4; ni++)
        acc[mi][ni] = __builtin_amdgcn_mfma_f32_16x16x32_bf16(af[mi], bfr[ni], acc[mi][ni], 0, 0, 0);
    __syncthreads();
  }

  if (EPI == 0) {
    const int which = nb >> 12;        // 0=Q 1=K 2=V (BN=128 aligned to one head)
    const int h = (nb & 4095) >> 7;
    short* dst = (which == 0) ? Qb : ((which == 1) ? Kb : Vb);
#pragma unroll
    for (int ni = 0; ni < 4; ni++) {
      const int d = wn + ni * 16 + c;
      const float bv = bias[nb + d];
#pragma unroll
      for (int mi = 0; mi < 4; mi++)
#pragma unroll
        for (int j = 0; j < 4; j++) {
          const int row = m0 + wm + mi * 16 + g * 4 + j;
          dst[((size_t)h * S_LEN + row) * HD + d] = f2bf(acc[mi][ni][j] + bv);
        }
    }
  } else {
#pragma unroll
    for (int ni = 0; ni < 4; ni++) {
      const int n = nb + wn + ni * 16 + c;
#pragma unroll
      for (int mi = 0; mi < 4; mi++)
#pragma unroll
        for (int j = 0; j < 4; j++) {
          const int row = m0 + wm + mi * 16 + g * 4 + j;
          Cout[(size_t)row * N + n] = acc[mi][ni][j];
        }
    }
  }
}

// ---------------- RoPE in-place on Q,K; folds 1/sqrt(HD) into Q ----------------
__global__ void rope_kernel(const int* __restrict__ positions,
                            short* __restrict__ Qb, short* __restrict__ Kb)
{
  const int s = blockIdx.x;
  const int h = blockIdx.y * 4 + threadIdx.y;
  const int d = threadIdx.x;                      // 0..63 (pair d, d+64)
  const float pos = (float)positions[s];
  // inv_freq = 10000^(-d/64) = exp2(-d * log2(10000)/64)
  const float inv_freq = exp2f(-(float)d * 0.20762050593046014f);
  const float ang = pos * inv_freq;
  float sn, cs;
  sincosf(ang, &sn, &cs);
  const size_t base = ((size_t)h * S_LEN + s) * HD + d;
  const float scale = 0.08838834764831845f;       // 1/sqrt(128)
  float x1 = bf2f(Qb[base]), x2 = bf2f(Qb[base + 64]);
  Qb[base]      = f2bf((x1 * cs - x2 * sn) * scale);
  Qb[base + 64] = f2bf((x2 * cs + x1 * sn) * scale);
  x1 = bf2f(Kb[base]); x2 = bf2f(Kb[base + 64]);
  Kb[base]      = f2bf(x1 * cs - x2 * sn);
  Kb[base + 64] = f2bf(x2 * cs + x1 * sn);
}

// ---------------- V -> Vt [NH][HD][S] ----------------
__global__ __launch_bounds__(256)
void vtrans_kernel(const short* __restrict__ V, short* __restrict__ Vt)
{
  __shared__ short tile[64][72];
  const int h = blockIdx.z;
  const int s0 = blockIdx.x * 64;
  const int d0 = blockIdx.y * 64;
  const int tx = threadIdx.x & 63, ty = threadIdx.x >> 6;
  for (int r = ty; r < 64; r += 4)
    tile[r][tx] = V[((size_t)h * S_LEN + s0 + r) * HD + d0 + tx];
  __syncthreads();
  for (int r = ty; r < 64; r += 4)
    Vt[((size_t)h * HD + d0 + r) * S_LEN + s0 + tx] = tile[tx][r];
}

// ---------------- causal flash attention ----------------
// grid (S/128, NH), 8 waves; wave w owns q rows [q0+16w, +16). KVBLK=32.
__global__ __launch_bounds__(512)
void attn_kernel(const short* __restrict__ Q, const short* __restrict__ Kb,
                 const short* __restrict__ Vt, float* __restrict__ attn_out)
{
  __shared__ short Plds[8][16][40];
  const int h = blockIdx.y;
  const int q0 = blockIdx.x * 128;
  const int t = threadIdx.x;
  const int w = t >> 6, lane = t & 63, c = lane & 15, g = lane >> 4;
  const short* Qh = Q  + (size_t)h * S_LEN * HD;
  const short* Kh = Kb + (size_t)h * S_LEN * HD;
  const short* Vh = Vt + (size_t)h * HD * S_LEN;

  const int qrow = q0 + w * 16 + c;       // A-frag row
  s16x8 qf[4];
#pragma unroll
  for (int di = 0; di < 4; di++)
    qf[di] = *(const s16x8*)&Qh[(size_t)qrow * HD + di * 32 + g * 8];

  f32x4 o[8];
#pragma unroll
  for (int dt = 0; dt < 8; dt++) o[dt] = (f32x4){0.f, 0.f, 0.f, 0.f};
  float m_r[4], l_r[4];
#pragma unroll
  for (int j = 0; j < 4; j++) { m_r[j] = -3.0e38f; l_r[j] = 0.f; }

  const int nt = q0 / 32 + 4;             // uniform over block (causal bound)
  for (int kt = 0; kt < nt; kt++) {
    const int kb = kt * 32;
    f32x4 s0 = (f32x4){0.f, 0.f, 0.f, 0.f}, s1 = (f32x4){0.f, 0.f, 0.f, 0.f};
#pragma unroll
    for (int di = 0; di < 4; di++) {
      s16x8 kf0 = *(const s16x8*)&Kh[(size_t)(kb + c) * HD + di * 32 + g * 8];
      s16x8 kf1 = *(const s16x8*)&Kh[(size_t)(kb + 16 + c) * HD + di * 32 + g * 8];
      s0 = __builtin_amdgcn_mfma_f32_16x16x32_bf16(qf[di], kf0, s0, 0, 0, 0);
      s1 = __builtin_amdgcn_mfma_f32_16x16x32_bf16(qf[di], kf1, s1, 0, 0, 0);
    }
    float p0[4], p1[4], alpha[4];
#pragma unroll
    for (int j = 0; j < 4; j++) {
      const int qg = q0 + w * 16 + g * 4 + j;
      const float v0 = (kb + c      <= qg) ? s0[j] : -__builtin_inff();
      const float v1 = (kb + 16 + c <= qg) ? s1[j] : -__builtin_inff();
      float mx = fmaxf(v0, v1);
#pragma unroll
      for (int off = 1; off < 16; off <<= 1) mx = fmaxf(mx, __shfl_xor(mx, off, 64));
      const float mn = fmaxf(m_r[j], mx);
      alpha[j] = __expf(m_r[j] - mn);
      p0[j] = __expf(v0 - mn);
      p1[j] = __expf(v1 - mn);
      float rs = p0[j] + p1[j];
#pragma unroll
      for (int off = 1; off < 16; off <<= 1) rs += __shfl_xor(rs, off, 64);
      l_r[j] = l_r[j] * alpha[j] + rs;
      m_r[j] = mn;
    }
#pragma unroll
    for (int dt = 0; dt < 8; dt++)
#pragma unroll
      for (int j = 0; j < 4; j++) o[dt][j] *= alpha[j];
    // transpose P through per-wave LDS (C-layout -> A-layout)
    __syncthreads();                       // WAR: prior iter's P reads done
#pragma unroll
    for (int j = 0; j < 4; j++) {
      Plds[w][g * 4 + j][c]      = f2bf(p0[j]);
      Plds[w][g * 4 + j][16 + c] = f2bf(p1[j]);
    }
    __syncthreads();
    const s16x8 pa = *(const s16x8*)&Plds[w][c][g * 8];
#pragma unroll
    for (int dt = 0; dt < 8; dt++) {
      s16x8 vf = *(const s16x8*)&Vh[(size_t)(dt * 16 + c) * S_LEN + kb + g * 8];
      o[dt] = __builtin_amdgcn_mfma_f32_16x16x32_bf16(pa, vf, o[dt], 0, 0, 0);
    }
  }
  float inv_l[4];
#pragma unroll
  for (int j = 0; j < 4; j++) inv_l[j] = 1.0f / l_r[j];
#pragma unroll
  for (int dt = 0; dt < 8; dt++)
#pragma unroll
    for (int j = 0; j < 4; j++) {
      const int row = q0 + w * 16 + g * 4 + j;
      attn_out[(size_t)row * HID + h * HD + dt * 16 + c] = o[dt][j] * inv_l[j];
    }
}

extern "C" void kernel_launch(void* const* d_in, const int* in_sizes, int n_in,
                              void* d_out, int out_size, void* d_ws, size_t ws_size,
                              hipStream_t stream)
{
  const int*   positions = (const int*)d_in[0];
  const float* hidden    = (const float*)d_in[1];
  const float* w_qkv     = (const float*)d_in[2];
  const float* b_qkv     = (const float*)d_in[3];
  const float* w_o       = (const float*)d_in[4];
  float* out = (float*)d_out;

  char* ws = (char*)d_ws;
  short* Qb  = (short*)(ws);                         // 16 MB  [NH][S][HD] bf16
  short* Kb  = (short*)(ws + (size_t)(16 << 20));    // 16 MB
  short* Vb  = (short*)(ws + (size_t)(32 << 20));    // 16 MB
  short* Vt  = (short*)(ws + (size_t)(48 << 20));    // 16 MB  [NH][HD][S]
  float* attn = (float*)(ws + (size_t)(64 << 20));   // 32 MB  [S][HID] f32

  gemm_kernel<0><<<dim3(16, 96), 256, 0, stream>>>(hidden, w_qkv, b_qkv, 3 * HID,
                                                   Qb, Kb, Vb, nullptr);
  rope_kernel<<<dim3(S_LEN, NH / 4), dim3(64, 4), 0, stream>>>(positions, Qb, Kb);
  vtrans_kernel<<<dim3(S_LEN / 64, HD / 64, NH), 256, 0, stream>>>(Vb, Vt);
  attn_kernel<<<dim3(S_LEN / 128, NH), 512, 0, stream>>>(Qb, Kb, Vt, attn);
  gemm_kernel<1><<<dim3(16, 32), 256, 0, stream>>>(attn, w_o, nullptr, HID,
                                                   nullptr, nullptr, nullptr, out);
}

// Round 3
// 629.670 us; speedup vs baseline: 1.8421x; 1.8421x over previous
//
#include <hip/hip_runtime.h>
#include <hip/hip_bf16.h>

#define S_LEN 2048
#define HID   4096
#define NH    32
#define HD    128
#define KD    4096

typedef __attribute__((ext_vector_type(4))) float f32x4;
typedef __attribute__((ext_vector_type(8))) short s16x8;
typedef __attribute__((ext_vector_type(4))) short s16x4;

#define AS1 __attribute__((address_space(1)))
#define AS3 __attribute__((address_space(3)))

__device__ __forceinline__ void gl_lds16(const void* g, void* l) {
  __builtin_amdgcn_global_load_lds((const AS1 void*)g, (AS3 void*)l, 16, 0, 0);
}

__device__ inline short f2bf(float f) {
  union { float f; unsigned u; } v; v.f = f;
  return (short)((v.u + 0x7fffu + ((v.u >> 16) & 1u)) >> 16);
}
__device__ inline float bf2f(short s) {
  union { unsigned u; float f; } v; v.u = ((unsigned)(unsigned short)s) << 16;
  return v.f;
}

// ============ one-time converts (fast path) ============
__global__ __launch_bounds__(256)
void cvt_kernel(const float* __restrict__ A, short* __restrict__ Ab) {
  const size_t i = ((size_t)blockIdx.x * 256 + threadIdx.x) * 8;
  f32x4 v0 = *(const f32x4*)&A[i];
  f32x4 v1 = *(const f32x4*)&A[i + 4];
  s16x8 r;
  r[0]=f2bf(v0[0]); r[1]=f2bf(v0[1]); r[2]=f2bf(v0[2]); r[3]=f2bf(v0[3]);
  r[4]=f2bf(v1[0]); r[5]=f2bf(v1[1]); r[6]=f2bf(v1[2]); r[7]=f2bf(v1[3]);
  *(s16x8*)&Ab[i] = r;
}

// W [KD][N] f32 -> Wt [N][KD] bf16
__global__ __launch_bounds__(256)
void transcvt_kernel(const float* __restrict__ W, short* __restrict__ Wt, const int N) {
  __shared__ float tile[64][65];
  const int k0 = blockIdx.x * 64, n0 = blockIdx.y * 64;
  const int t = threadIdx.x;
#pragma unroll
  for (int i = 0; i < 16; ++i) {
    const int e = i * 256 + t;
    const int k = e >> 6, n = e & 63;
    tile[n][k] = W[(size_t)(k0 + k) * N + n0 + n];
  }
  __syncthreads();
  const int nn = t >> 2, ks = (t & 3) * 16;
  s16x8 a, b;
#pragma unroll
  for (int i = 0; i < 8; i++) a[i] = f2bf(tile[nn][ks + i]);
#pragma unroll
  for (int i = 0; i < 8; i++) b[i] = f2bf(tile[nn][ks + 8 + i]);
  *(s16x8*)&Wt[(size_t)(n0 + nn) * KD + k0 + ks]     = a;
  *(s16x8*)&Wt[(size_t)(n0 + nn) * KD + k0 + ks + 8] = b;
}

// ============ fast GEMM (m97 structure): A bf16 [M][KD], Bt bf16 [N][KD] ============
template<int EPI>
__global__ __launch_bounds__(256)
void gemm2_kernel(const short* __restrict__ A, const short* __restrict__ Bt,
                  const float* __restrict__ bias, const int N,
                  short* __restrict__ Qb, short* __restrict__ Kb, short* __restrict__ Vb,
                  float* __restrict__ Cout)
{
  __shared__ short As[128][32];
  __shared__ short Bs[128][32];
  const int m0 = blockIdx.x * 128, nb = blockIdx.y * 128;
  const int t = threadIdx.x, w = t >> 6, lane = t & 63, c = lane & 15, g = lane >> 4;
  const int wm = (w >> 1) * 64, wn = (w & 1) * 64;

  f32x4 acc[4][4];
#pragma unroll
  for (int i = 0; i < 4; i++)
#pragma unroll
    for (int j = 0; j < 4; j++) acc[i][j] = (f32x4){0.f, 0.f, 0.f, 0.f};

  const char* Abase = (const char*)A  + (size_t)m0 * (KD * 2);
  const char* Bbase = (const char*)Bt + (size_t)nb * (KD * 2);
  char* As3 = (char*)&As[0][0];
  char* Bs3 = (char*)&Bs[0][0];

  for (int k0 = 0; k0 < KD; k0 += 32) {
#pragma unroll
    for (int i = 0; i < 2; ++i) {
      const int ch = (w * 2 + i) * 64 + lane;       // 0..511
      const int row = ch >> 2, c16 = ch & 3;
      gl_lds16(Abase + (size_t)row * (KD * 2) + k0 * 2 + c16 * 16, As3 + (w * 2 + i) * 1024);
      gl_lds16(Bbase + (size_t)row * (KD * 2) + k0 * 2 + c16 * 16, Bs3 + (w * 2 + i) * 1024);
    }
    __syncthreads();
    s16x8 af[4], bfr[4];
#pragma unroll
    for (int i = 0; i < 4; i++) af[i]  = *(const s16x8*)&As[wm + i * 16 + c][g * 8];
#pragma unroll
    for (int i = 0; i < 4; i++) bfr[i] = *(const s16x8*)&Bs[wn + i * 16 + c][g * 8];
#pragma unroll
    for (int mi = 0; mi < 4; mi++)
#pragma unroll
      for (int ni = 0; ni < 4; ni++)
        acc[mi][ni] = __builtin_amdgcn_mfma_f32_16x16x32_bf16(af[mi], bfr[ni], acc[mi][ni], 0, 0, 0);
    __syncthreads();
  }

  if (EPI == 0) {
    const int which = nb >> 12;
    const int h = (nb & 4095) >> 7;
    short* dst = (which == 0) ? Qb : ((which == 1) ? Kb : Vb);
#pragma unroll
    for (int ni = 0; ni < 4; ni++) {
      const int d = wn + ni * 16 + c;
      const float bv = bias[nb + d];
#pragma unroll
      for (int mi = 0; mi < 4; mi++)
#pragma unroll
        for (int j = 0; j < 4; j++) {
          const int row = m0 + wm + mi * 16 + g * 4 + j;
          dst[((size_t)h * S_LEN + row) * HD + d] = f2bf(acc[mi][ni][j] + bv);
        }
    }
  } else {
#pragma unroll
    for (int ni = 0; ni < 4; ni++) {
      const int n = nb + wn + ni * 16 + c;
#pragma unroll
      for (int mi = 0; mi < 4; mi++)
#pragma unroll
        for (int j = 0; j < 4; j++) {
          const int row = m0 + wm + mi * 16 + g * 4 + j;
          Cout[(size_t)row * N + n] = acc[mi][ni][j];
        }
    }
  }
}

// ============ fallback GEMM (reg-staged, r2-proven). ABF16: A is bf16 ============
template<int EPI, int ABF16>
__global__ __launch_bounds__(256)
void gemm_kernel(const void* __restrict__ Av, const float* __restrict__ B,
                 const float* __restrict__ bias, const int N,
                 short* __restrict__ Qb, short* __restrict__ Kb, short* __restrict__ Vb,
                 float* __restrict__ Cout)
{
  __shared__ short As[128][40];
  __shared__ short Bs[128][40];
  const int m0 = blockIdx.x * 128;
  const int nb = blockIdx.y * 128;
  const int t  = threadIdx.x;
  const int w = t >> 6, lane = t & 63, c = lane & 15, g = lane >> 4;
  const int wm = (w >> 1) * 64, wn = (w & 1) * 64;

  f32x4 acc[4][4];
#pragma unroll
  for (int i = 0; i < 4; i++)
#pragma unroll
    for (int j = 0; j < 4; j++) acc[i][j] = (f32x4){0.f, 0.f, 0.f, 0.f};

  const int ar = t >> 3;
  const int ac = (t & 7) * 4;
  const int bn = t & 127;
  const int bkq = (t >> 7) * 16;

  for (int k0 = 0; k0 < KD; k0 += 32) {
#pragma unroll
    for (int rr = 0; rr < 4; rr++) {
      const int row = rr * 32 + ar;
      if (ABF16) {
        *(s16x4*)&As[row][ac] =
          *(const s16x4*)((const short*)Av + (size_t)(m0 + row) * KD + k0 + ac);
      } else {
        f32x4 v = *(const f32x4*)((const float*)Av + (size_t)(m0 + row) * KD + k0 + ac);
        s16x4 pk;
        pk[0] = f2bf(v[0]); pk[1] = f2bf(v[1]); pk[2] = f2bf(v[2]); pk[3] = f2bf(v[3]);
        *(s16x4*)&As[row][ac] = pk;
      }
    }
    const float* pB = B + (size_t)(k0 + bkq) * N + nb + bn;
    s16x8 b0, b1;
#pragma unroll
    for (int i = 0; i < 8; i++) b0[i] = f2bf(pB[(size_t)i * N]);
#pragma unroll
    for (int i = 0; i < 8; i++) b1[i] = f2bf(pB[(size_t)(i + 8) * N]);
    *(s16x8*)&Bs[bn][bkq]     = b0;
    *(s16x8*)&Bs[bn][bkq + 8] = b1;
    __syncthreads();
    s16x8 af[4], bfr[4];
#pragma unroll
    for (int i = 0; i < 4; i++) af[i]  = *(const s16x8*)&As[wm + i * 16 + c][g * 8];
#pragma unroll
    for (int i = 0; i < 4; i++) bfr[i] = *(const s16x8*)&Bs[wn + i * 16 + c][g * 8];
#pragma unroll
    for (int mi = 0; mi < 4; mi++)
#pragma unroll
      for (int ni = 0; ni < 4; ni++)
        acc[mi][ni] = __builtin_amdgcn_mfma_f32_16x16x32_bf16(af[mi], bfr[ni], acc[mi][ni], 0, 0, 0);
    __syncthreads();
  }

  if (EPI == 0) {
    const int which = nb >> 12;
    const int h = (nb & 4095) >> 7;
    short* dst = (which == 0) ? Qb : ((which == 1) ? Kb : Vb);
#pragma unroll
    for (int ni = 0; ni < 4; ni++) {
      const int d = wn + ni * 16 + c;
      const float bv = bias[nb + d];
#pragma unroll
      for (int mi = 0; mi < 4; mi++)
#pragma unroll
        for (int j = 0; j < 4; j++) {
          const int row = m0 + wm + mi * 16 + g * 4 + j;
          dst[((size_t)h * S_LEN + row) * HD + d] = f2bf(acc[mi][ni][j] + bv);
        }
    }
  } else {
#pragma unroll
    for (int ni = 0; ni < 4; ni++) {
      const int n = nb + wn + ni * 16 + c;
#pragma unroll
      for (int mi = 0; mi < 4; mi++)
#pragma unroll
        for (int j = 0; j < 4; j++) {
          const int row = m0 + wm + mi * 16 + g * 4 + j;
          Cout[(size_t)row * N + n] = acc[mi][ni][j];
        }
    }
  }
}

// ============ RoPE (in-place, folds 1/sqrt(HD) into Q) ============
__global__ void rope_kernel(const int* __restrict__ positions,
                            short* __restrict__ Qb, short* __restrict__ Kb)
{
  const int s = blockIdx.x;
  const int h = blockIdx.y * 4 + threadIdx.y;
  const int d = threadIdx.x;
  const float pos = (float)positions[s];
  const float inv_freq = exp2f(-(float)d * 0.20762050593046014f);
  const float ang = pos * inv_freq;
  float sn, cs;
  sincosf(ang, &sn, &cs);
  const size_t base = ((size_t)h * S_LEN + s) * HD + d;
  const float scale = 0.08838834764831845f;
  float x1 = bf2f(Qb[base]), x2 = bf2f(Qb[base + 64]);
  Qb[base]      = f2bf((x1 * cs - x2 * sn) * scale);
  Qb[base + 64] = f2bf((x2 * cs + x1 * sn) * scale);
  x1 = bf2f(Kb[base]); x2 = bf2f(Kb[base + 64]);
  Kb[base]      = f2bf(x1 * cs - x2 * sn);
  Kb[base + 64] = f2bf(x2 * cs + x1 * sn);
}

// ============ V -> Vt [NH][HD][S] ============
__global__ __launch_bounds__(256)
void vtrans_kernel(const short* __restrict__ V, short* __restrict__ Vt)
{
  __shared__ short tile[64][72];
  const int h = blockIdx.z;
  const int s0 = blockIdx.x * 64;
  const int d0 = blockIdx.y * 64;
  const int tx = threadIdx.x & 63, ty = threadIdx.x >> 6;
  for (int r = ty; r < 64; r += 4)
    tile[r][tx] = V[((size_t)h * S_LEN + s0 + r) * HD + d0 + tx];
  __syncthreads();
  for (int r = ty; r < 64; r += 4)
    Vt[((size_t)h * HD + d0 + r) * S_LEN + s0 + tx] = tile[tx][r];
}

// ============ causal flash attention v2: LDS-staged K/V, double-buffered ============
// grid (S/128, NH), 8 waves; wave w owns q rows [q0+16w,+16). KVBLK=32.
__global__ __launch_bounds__(512)
void attn_kernel(const short* __restrict__ Q, const short* __restrict__ Kg,
                 const short* __restrict__ Vtg, short* __restrict__ attn_out)
{
  __shared__ short Ks[2][32][136];   // [kv][d], row stride 272B (16B-aligned, bank-balanced)
  __shared__ short Vs[2][128][40];   // [d][kv], row stride 80B
  __shared__ short Plds[8][16][40];  // per-wave P transpose
  const int h = blockIdx.y;
  const int q0 = blockIdx.x * 128;
  const int t = threadIdx.x;
  const int w = t >> 6, lane = t & 63, c = lane & 15, g = lane >> 4;
  const short* Qh = Q   + (size_t)h * S_LEN * HD;
  const short* Kh = Kg  + (size_t)h * S_LEN * HD;
  const short* Vh = Vtg + (size_t)h * HD * S_LEN;

  // staging assignments (block-wide: t = 0..511)
  const int krow = t >> 4, kc16 = t & 15;   // K tile: 32 rows x 16 chunks
  const int vrow = t >> 2, vc16 = t & 3;    // V tile: 128 rows x 4 chunks

  const int qrow = q0 + w * 16 + c;
  s16x8 qf[4];
#pragma unroll
  for (int di = 0; di < 4; di++)
    qf[di] = *(const s16x8*)&Qh[(size_t)qrow * HD + di * 32 + g * 8];

  f32x4 o[8];
#pragma unroll
  for (int dt = 0; dt < 8; dt++) o[dt] = (f32x4){0.f, 0.f, 0.f, 0.f};
  float m_r[4], l_r[4];
#pragma unroll
  for (int j = 0; j < 4; j++) { m_r[j] = -3.0e38f; l_r[j] = 0.f; }

  const int nt = q0 / 32 + 4;

  // prologue: stage tile 0 into buf 0
  {
    s16x8 gK = *(const s16x8*)&Kh[(size_t)krow * HD + kc16 * 8];
    s16x8 gV = *(const s16x8*)&Vh[(size_t)vrow * S_LEN + vc16 * 8];
    *(s16x8*)&Ks[0][krow][kc16 * 8] = gK;
    *(s16x8*)&Vs[0][vrow][vc16 * 8] = gV;
  }
  __syncthreads();

  for (int kt = 0; kt < nt; kt++) {
    const int cur = kt & 1;
    const int kb = kt * 32;
    // T14: issue next tile's global loads before compute
    s16x8 gK, gV;
    if (kt + 1 < nt) {
      gK = *(const s16x8*)&Kh[(size_t)(kb + 32 + krow) * HD + kc16 * 8];
      gV = *(const s16x8*)&Vh[(size_t)vrow * S_LEN + kb + 32 + vc16 * 8];
    }
    // QK^T from LDS
    f32x4 s0 = (f32x4){0.f, 0.f, 0.f, 0.f}, s1 = (f32x4){0.f, 0.f, 0.f, 0.f};
#pragma unroll
    for (int di = 0; di < 4; di++) {
      s16x8 kf0 = *(const s16x8*)&Ks[cur][c][di * 32 + g * 8];
      s16x8 kf1 = *(const s16x8*)&Ks[cur][16 + c][di * 32 + g * 8];
      s0 = __builtin_amdgcn_mfma_f32_16x16x32_bf16(qf[di], kf0, s0, 0, 0, 0);
      s1 = __builtin_amdgcn_mfma_f32_16x16x32_bf16(qf[di], kf1, s1, 0, 0, 0);
    }
    float p0[4], p1[4], alpha[4];
#pragma unroll
    for (int j = 0; j < 4; j++) {
      const int qg = q0 + w * 16 + g * 4 + j;
      const float v0 = (kb + c      <= qg) ? s0[j] : -__builtin_inff();
      const float v1 = (kb + 16 + c <= qg) ? s1[j] : -__builtin_inff();
      float mx = fmaxf(v0, v1);
#pragma unroll
      for (int off = 1; off < 16; off <<= 1) mx = fmaxf(mx, __shfl_xor(mx, off, 64));
      const float mn = fmaxf(m_r[j], mx);
      alpha[j] = __expf(m_r[j] - mn);
      p0[j] = __expf(v0 - mn);
      p1[j] = __expf(v1 - mn);
      float rs = p0[j] + p1[j];
#pragma unroll
      for (int off = 1; off < 16; off <<= 1) rs += __shfl_xor(rs, off, 64);
      l_r[j] = l_r[j] * alpha[j] + rs;
      m_r[j] = mn;
    }
#pragma unroll
    for (int dt = 0; dt < 8; dt++)
#pragma unroll
      for (int j = 0; j < 4; j++) o[dt][j] *= alpha[j];
    // per-wave P transpose (no block barrier needed; within-wave LDS order)
#pragma unroll
    for (int j = 0; j < 4; j++) {
      Plds[w][g * 4 + j][c]      = f2bf(p0[j]);
      Plds[w][g * 4 + j][16 + c] = f2bf(p1[j]);
    }
    const s16x8 pa = *(const s16x8*)&Plds[w][c][g * 8];
#pragma unroll
    for (int dt = 0; dt < 8; dt++) {
      s16x8 vf = *(const s16x8*)&Vs[cur][dt * 16 + c][g * 8];
      o[dt] = __builtin_amdgcn_mfma_f32_16x16x32_bf16(pa, vf, o[dt], 0, 0, 0);
    }
    __syncthreads();                // all reads of buf[cur^1] (prev iter) + buf[cur] done
    if (kt + 1 < nt) {
      *(s16x8*)&Ks[cur ^ 1][krow][kc16 * 8] = gK;
      *(s16x8*)&Vs[cur ^ 1][vrow][vc16 * 8] = gV;
    }
    __syncthreads();                // staged tile visible
  }

  float inv_l[4];
#pragma unroll
  for (int j = 0; j < 4; j++) inv_l[j] = 1.0f / l_r[j];
#pragma unroll
  for (int dt = 0; dt < 8; dt++)
#pragma unroll
    for (int j = 0; j < 4; j++) {
      const int row = q0 + w * 16 + g * 4 + j;
      attn_out[(size_t)row * HID + h * HD + dt * 16 + c] = f2bf(o[dt][j] * inv_l[j]);
    }
}

extern "C" void kernel_launch(void* const* d_in, const int* in_sizes, int n_in,
                              void* d_out, int out_size, void* d_ws, size_t ws_size,
                              hipStream_t stream)
{
  const int*   positions = (const int*)d_in[0];
  const float* hidden    = (const float*)d_in[1];
  const float* w_qkv     = (const float*)d_in[2];
  const float* b_qkv     = (const float*)d_in[3];
  const float* w_o       = (const float*)d_in[4];
  float* out = (float*)d_out;

  char* ws = (char*)d_ws;
  const size_t MB = (size_t)1 << 20;

  if (ws_size >= 224 * MB) {
    short* Ah    = (short*)(ws);                 // 16 MB  bf16 [S][KD]
    short* Wqt   = (short*)(ws + 16 * MB);       // 96 MB  bf16 [3*HID][KD]
    short* Wot   = (short*)(ws + 112 * MB);      // 32 MB  bf16 [HID][KD]
    short* Qb    = (short*)(ws + 144 * MB);      // 16 MB
    short* Kb    = (short*)(ws + 160 * MB);      // 16 MB
    short* Vb    = (short*)(ws + 176 * MB);      // 16 MB
    short* Vt    = (short*)(ws + 192 * MB);      // 16 MB
    short* attnb = (short*)(ws + 208 * MB);      // 16 MB  bf16 [S][HID]

    cvt_kernel<<<4096, 256, 0, stream>>>(hidden, Ah);
    transcvt_kernel<<<dim3(KD / 64, 3 * HID / 64), 256, 0, stream>>>(w_qkv, Wqt, 3 * HID);
    transcvt_kernel<<<dim3(KD / 64, HID / 64), 256, 0, stream>>>(w_o, Wot, HID);
    gemm2_kernel<0><<<dim3(16, 96), 256, 0, stream>>>(Ah, Wqt, b_qkv, 3 * HID,
                                                      Qb, Kb, Vb, nullptr);
    rope_kernel<<<dim3(S_LEN, NH / 4), dim3(64, 4), 0, stream>>>(positions, Qb, Kb);
    vtrans_kernel<<<dim3(S_LEN / 64, HD / 64, NH), 256, 0, stream>>>(Vb, Vt);
    attn_kernel<<<dim3(S_LEN / 128, NH), 512, 0, stream>>>(Qb, Kb, Vt, attnb);
    gemm2_kernel<1><<<dim3(16, 32), 256, 0, stream>>>(attnb, Wot, nullptr, HID,
                                                      nullptr, nullptr, nullptr, out);
  } else {
    short* Qb    = (short*)(ws);
    short* Kb    = (short*)(ws + 16 * MB);
    short* Vb    = (short*)(ws + 32 * MB);
    short* Vt    = (short*)(ws + 48 * MB);
    short* attnb = (short*)(ws + 64 * MB);

    gemm_kernel<0, 0><<<dim3(16, 96), 256, 0, stream>>>(hidden, w_qkv, b_qkv, 3 * HID,
                                                        Qb, Kb, Vb, nullptr);
    rope_kernel<<<dim3(S_LEN, NH / 4), dim3(64, 4), 0, stream>>>(positions, Qb, Kb);
    vtrans_kernel<<<dim3(S_LEN / 64, HD / 64, NH), 256, 0, stream>>>(Vb, Vt);
    attn_kernel<<<dim3(S_LEN / 128, NH), 512, 0, stream>>>(Qb, Kb, Vt, attnb);
    gemm_kernel<1, 1><<<dim3(16, 32), 256, 0, stream>>>(attnb, w_o, nullptr, HID,
                                                        nullptr, nullptr, nullptr, out);
  }
}

// Round 4
// 623.854 us; speedup vs baseline: 1.8593x; 1.0093x over previous
//
#include <hip/hip_runtime.h>
#include <hip/hip_bf16.h>

#define S_LEN 2048
#define HID   4096
#define NH    32
#define HD    128
#define KD    4096

typedef __attribute__((ext_vector_type(4))) float f32x4;
typedef __attribute__((ext_vector_type(8))) short s16x8;
typedef __attribute__((ext_vector_type(4))) short s16x4;

#define AS1 __attribute__((address_space(1)))
#define AS3 __attribute__((address_space(3)))

__device__ __forceinline__ void gl_lds16(const void* g, void* l) {
  __builtin_amdgcn_global_load_lds((const AS1 void*)g, (AS3 void*)l, 16, 0, 0);
}

__device__ inline short f2bf(float f) {
  union { float f; unsigned u; } v; v.f = f;
  return (short)((v.u + 0x7fffu + ((v.u >> 16) & 1u)) >> 16);
}
__device__ inline float bf2f(short s) {
  union { unsigned u; float f; } v; v.u = ((unsigned)(unsigned short)s) << 16;
  return v.f;
}

// XOR swizzle (involution) within each 256B block of a [rows][32] bf16 tile (64B rows)
__device__ __forceinline__ int swz(int a) { return a ^ (((a >> 7) & 3) << 4); }

// ============ one-time converts ============
__global__ __launch_bounds__(256)
void cvt_kernel(const float* __restrict__ A, short* __restrict__ Ab) {
  const size_t i = ((size_t)blockIdx.x * 256 + threadIdx.x) * 8;
  f32x4 v0 = *(const f32x4*)&A[i];
  f32x4 v1 = *(const f32x4*)&A[i + 4];
  s16x8 r;
  r[0]=f2bf(v0[0]); r[1]=f2bf(v0[1]); r[2]=f2bf(v0[2]); r[3]=f2bf(v0[3]);
  r[4]=f2bf(v1[0]); r[5]=f2bf(v1[1]); r[6]=f2bf(v1[2]); r[7]=f2bf(v1[3]);
  *(s16x8*)&Ab[i] = r;
}

// W [KD][N] f32 -> Wt [N][KD] bf16
__global__ __launch_bounds__(256)
void transcvt_kernel(const float* __restrict__ W, short* __restrict__ Wt, const int N) {
  __shared__ float tile[64][65];
  const int k0 = blockIdx.x * 64, n0 = blockIdx.y * 64;
  const int t = threadIdx.x;
#pragma unroll
  for (int i = 0; i < 16; ++i) {
    const int e = i * 256 + t;
    const int k = e >> 6, n = e & 63;
    tile[n][k] = W[(size_t)(k0 + k) * N + n0 + n];
  }
  __syncthreads();
  const int nn = t >> 2, ks = (t & 3) * 16;
  s16x8 a, b;
#pragma unroll
  for (int i = 0; i < 8; i++) a[i] = f2bf(tile[nn][ks + i]);
#pragma unroll
  for (int i = 0; i < 8; i++) b[i] = f2bf(tile[nn][ks + 8 + i]);
  *(s16x8*)&Wt[(size_t)(n0 + nn) * KD + k0 + ks]     = a;
  *(s16x8*)&Wt[(size_t)(n0 + nn) * KD + k0 + ks + 8] = b;
}

// ============ QKV GEMM v3: 256x256 tile, BK=32, 4-deep LDS ring, counted vmcnt ============
// A bf16 [2048][4096], Bt bf16 [12288][4096]; writes Q/K/V bf16 head-major + bias.
// 512 threads = 8 waves (2Mx4N), per-wave C = 128x64 (acc[8][4]).
__global__ __launch_bounds__(512, 2)
void gemm3_kernel(const short* __restrict__ A, const short* __restrict__ Bt,
                  const float* __restrict__ bias,
                  short* __restrict__ Qb, short* __restrict__ Kb, short* __restrict__ Vb)
{
  __shared__ char smem3[131072] __attribute__((aligned(16)));
  const int KD2 = KD * 2;

  // XCD-chunked bijective block mapping: 384 blocks = 8 xcd * (6 ncols * 8 mrows)
  const int bid = blockIdx.x;
  const int xcd = bid & 7, idx = bid >> 3;
  const int mb = idx & 7;
  const int nbcol = xcd * 6 + (idx >> 3);
  const int m0 = mb * 256, nb0 = nbcol * 256;

  const int t = threadIdx.x;
  const int lane = t & 63, c = lane & 15, g = lane >> 4;
  const int w = t >> 6, wr = w >> 2, wc = w & 3;

  // ---- staging source pointers (pre-swizzled so linear gl_lds dest == swizzled layout) ----
  const char* Abase = (const char*)A  + (size_t)m0  * KD2;
  const char* Bbase = (const char*)Bt + (size_t)nb0 * KD2;
  const int L0 = t * 16, L1 = 8192 + t * 16;
  const int lbA0 = swz(L0), lbA1 = swz(L1);
  const char* pA0 = Abase + (size_t)(lbA0 >> 6) * KD2 + (lbA0 & 63);
  const char* pA1 = Abase + (size_t)(lbA1 >> 6) * KD2 + (lbA1 & 63);
  const char* pB0 = Bbase + (size_t)(lbA0 >> 6) * KD2 + (lbA0 & 63);
  const char* pB1 = Bbase + (size_t)(lbA1 >> 6) * KD2 + (lbA1 & 63);

  // ---- swizzled ds_read offsets (per-lane, loop-invariant) ----
  int offA[8], offB[4];
#pragma unroll
  for (int mi = 0; mi < 8; ++mi) {
    const int la = (wr * 128 + mi * 16 + c) * 64 + g * 16;
    offA[mi] = swz(la);
  }
#pragma unroll
  for (int ni = 0; ni < 4; ++ni) {
    const int la = (wc * 64 + ni * 16 + c) * 64 + g * 16;
    offB[ni] = swz(la);
  }

  f32x4 acc[8][4];
#pragma unroll
  for (int mi = 0; mi < 8; ++mi)
#pragma unroll
    for (int ni = 0; ni < 4; ++ni) acc[mi][ni] = (f32x4){0.f, 0.f, 0.f, 0.f};

#define STAGE(kt, BUF) do {                                   \
    char* d_ = smem3 + (BUF) * 32768;                         \
    const size_t ko_ = (size_t)(kt) * 64;                     \
    gl_lds16(pA0 + ko_, d_ + t * 16);                         \
    gl_lds16(pA1 + ko_, d_ + 8192 + t * 16);                  \
    gl_lds16(pB0 + ko_, d_ + 16384 + t * 16);                 \
    gl_lds16(pB1 + ko_, d_ + 24576 + t * 16);                 \
  } while (0)

#define COMPUTE(BUF) do {                                     \
    const char* base_ = smem3 + (BUF) * 32768;                \
    s16x8 a_[8], b_[4];                                       \
    _Pragma("unroll")                                         \
    for (int mi = 0; mi < 8; ++mi) a_[mi] = *(const s16x8*)(base_ + offA[mi]); \
    _Pragma("unroll")                                         \
    for (int ni = 0; ni < 4; ++ni) b_[ni] = *(const s16x8*)(base_ + 16384 + offB[ni]); \
    __builtin_amdgcn_s_setprio(1);                            \
    _Pragma("unroll")                                         \
    for (int mi = 0; mi < 8; ++mi)                            \
      _Pragma("unroll")                                       \
      for (int ni = 0; ni < 4; ++ni)                          \
        acc[mi][ni] = __builtin_amdgcn_mfma_f32_16x16x32_bf16(a_[mi], b_[ni], acc[mi][ni], 0, 0, 0); \
    __builtin_amdgcn_s_setprio(0);                            \
  } while (0)

#define WAIT8 asm volatile("s_waitcnt vmcnt(8)" ::: "memory")
#define WAIT4 asm volatile("s_waitcnt vmcnt(4)" ::: "memory")
#define WAIT0 asm volatile("s_waitcnt vmcnt(0)" ::: "memory")
#define BARR  do { __builtin_amdgcn_s_barrier(); asm volatile("" ::: "memory"); } while (0)

  // prologue: 3 tiles in flight
  STAGE(0, 0); STAGE(1, 1); STAGE(2, 2);

  for (int t4 = 0; t4 < 124; t4 += 4) {
    WAIT8; BARR; STAGE(t4 + 3, 3); COMPUTE(0);
    WAIT8; BARR; STAGE(t4 + 4, 0); COMPUTE(1);
    WAIT8; BARR; STAGE(t4 + 5, 1); COMPUTE(2);
    WAIT8; BARR; STAGE(t4 + 6, 2); COMPUTE(3);
  }
  WAIT8; BARR; STAGE(127, 3); COMPUTE(0);   // kt=124
  WAIT8; BARR; COMPUTE(1);                  // kt=125
  WAIT4; BARR; COMPUTE(2);                  // kt=126
  WAIT0; BARR; COMPUTE(3);                  // kt=127

#undef STAGE
#undef COMPUTE
#undef WAIT8
#undef WAIT4
#undef WAIT0
#undef BARR

  // ---- epilogue: bias + bf16 scatter to head-major Q/K/V ----
#pragma unroll
  for (int ni = 0; ni < 4; ++ni) {
    const int ncol = nb0 + wc * 64 + ni * 16 + c;
    const int which = ncol >> 12;
    const int h = (ncol >> 7) & 31;
    const int dcl = ncol & 127;
    short* dst = (which == 0) ? Qb : ((which == 1) ? Kb : Vb);
    const float bv = bias[ncol];
#pragma unroll
    for (int mi = 0; mi < 8; ++mi)
#pragma unroll
      for (int jj = 0; jj < 4; ++jj) {
        const int row = m0 + wr * 128 + mi * 16 + g * 4 + jj;
        dst[((size_t)h * S_LEN + row) * HD + dcl] = f2bf(acc[mi][ni][jj] + bv);
      }
  }
}

// ============ m97-structure GEMM (O-proj): A bf16 [M][KD], Bt bf16 [N][KD] ============
template<int EPI>
__global__ __launch_bounds__(256)
void gemm2_kernel(const short* __restrict__ A, const short* __restrict__ Bt,
                  const float* __restrict__ bias, const int N,
                  short* __restrict__ Qb, short* __restrict__ Kb, short* __restrict__ Vb,
                  float* __restrict__ Cout)
{
  __shared__ short As[128][32];
  __shared__ short Bs[128][32];
  const int m0 = blockIdx.x * 128, nb = blockIdx.y * 128;
  const int t = threadIdx.x, w = t >> 6, lane = t & 63, c = lane & 15, g = lane >> 4;
  const int wm = (w >> 1) * 64, wn = (w & 1) * 64;

  f32x4 acc[4][4];
#pragma unroll
  for (int i = 0; i < 4; i++)
#pragma unroll
    for (int j = 0; j < 4; j++) acc[i][j] = (f32x4){0.f, 0.f, 0.f, 0.f};

  const char* Abase = (const char*)A  + (size_t)m0 * (KD * 2);
  const char* Bbase = (const char*)Bt + (size_t)nb * (KD * 2);
  char* As3 = (char*)&As[0][0];
  char* Bs3 = (char*)&Bs[0][0];

  for (int k0 = 0; k0 < KD; k0 += 32) {
#pragma unroll
    for (int i = 0; i < 2; ++i) {
      const int ch = (w * 2 + i) * 64 + lane;
      const int row = ch >> 2, c16 = ch & 3;
      gl_lds16(Abase + (size_t)row * (KD * 2) + k0 * 2 + c16 * 16, As3 + (w * 2 + i) * 1024);
      gl_lds16(Bbase + (size_t)row * (KD * 2) + k0 * 2 + c16 * 16, Bs3 + (w * 2 + i) * 1024);
    }
    __syncthreads();
    s16x8 af[4], bfr[4];
#pragma unroll
    for (int i = 0; i < 4; i++) af[i]  = *(const s16x8*)&As[wm + i * 16 + c][g * 8];
#pragma unroll
    for (int i = 0; i < 4; i++) bfr[i] = *(const s16x8*)&Bs[wn + i * 16 + c][g * 8];
#pragma unroll
    for (int mi = 0; mi < 4; mi++)
#pragma unroll
      for (int ni = 0; ni < 4; ni++)
        acc[mi][ni] = __builtin_amdgcn_mfma_f32_16x16x32_bf16(af[mi], bfr[ni], acc[mi][ni], 0, 0, 0);
    __syncthreads();
  }

  if (EPI == 0) {
    const int which = nb >> 12;
    const int h = (nb & 4095) >> 7;
    short* dst = (which == 0) ? Qb : ((which == 1) ? Kb : Vb);
#pragma unroll
    for (int ni = 0; ni < 4; ni++) {
      const int d = wn + ni * 16 + c;
      const float bv = bias[nb + d];
#pragma unroll
      for (int mi = 0; mi < 4; mi++)
#pragma unroll
        for (int j = 0; j < 4; j++) {
          const int row = m0 + wm + mi * 16 + g * 4 + j;
          dst[((size_t)h * S_LEN + row) * HD + d] = f2bf(acc[mi][ni][j] + bv);
        }
    }
  } else {
#pragma unroll
    for (int ni = 0; ni < 4; ni++) {
      const int n = nb + wn + ni * 16 + c;
#pragma unroll
      for (int mi = 0; mi < 4; mi++)
#pragma unroll
        for (int j = 0; j < 4; j++) {
          const int row = m0 + wm + mi * 16 + g * 4 + j;
          Cout[(size_t)row * N + n] = acc[mi][ni][j];
        }
    }
  }
}

// ============ fallback GEMM (reg-staged) ============
template<int EPI, int ABF16>
__global__ __launch_bounds__(256)
void gemm_kernel(const void* __restrict__ Av, const float* __restrict__ B,
                 const float* __restrict__ bias, const int N,
                 short* __restrict__ Qb, short* __restrict__ Kb, short* __restrict__ Vb,
                 float* __restrict__ Cout)
{
  __shared__ short As[128][40];
  __shared__ short Bs[128][40];
  const int m0 = blockIdx.x * 128;
  const int nb = blockIdx.y * 128;
  const int t  = threadIdx.x;
  const int w = t >> 6, lane = t & 63, c = lane & 15, g = lane >> 4;
  const int wm = (w >> 1) * 64, wn = (w & 1) * 64;

  f32x4 acc[4][4];
#pragma unroll
  for (int i = 0; i < 4; i++)
#pragma unroll
    for (int j = 0; j < 4; j++) acc[i][j] = (f32x4){0.f, 0.f, 0.f, 0.f};

  const int ar = t >> 3;
  const int ac = (t & 7) * 4;
  const int bn = t & 127;
  const int bkq = (t >> 7) * 16;

  for (int k0 = 0; k0 < KD; k0 += 32) {
#pragma unroll
    for (int rr = 0; rr < 4; rr++) {
      const int row = rr * 32 + ar;
      if (ABF16) {
        *(s16x4*)&As[row][ac] =
          *(const s16x4*)((const short*)Av + (size_t)(m0 + row) * KD + k0 + ac);
      } else {
        f32x4 v = *(const f32x4*)((const float*)Av + (size_t)(m0 + row) * KD + k0 + ac);
        s16x4 pk;
        pk[0] = f2bf(v[0]); pk[1] = f2bf(v[1]); pk[2] = f2bf(v[2]); pk[3] = f2bf(v[3]);
        *(s16x4*)&As[row][ac] = pk;
      }
    }
    const float* pB = B + (size_t)(k0 + bkq) * N + nb + bn;
    s16x8 b0, b1;
#pragma unroll
    for (int i = 0; i < 8; i++) b0[i] = f2bf(pB[(size_t)i * N]);
#pragma unroll
    for (int i = 0; i < 8; i++) b1[i] = f2bf(pB[(size_t)(i + 8) * N]);
    *(s16x8*)&Bs[bn][bkq]     = b0;
    *(s16x8*)&Bs[bn][bkq + 8] = b1;
    __syncthreads();
    s16x8 af[4], bfr[4];
#pragma unroll
    for (int i = 0; i < 4; i++) af[i]  = *(const s16x8*)&As[wm + i * 16 + c][g * 8];
#pragma unroll
    for (int i = 0; i < 4; i++) bfr[i] = *(const s16x8*)&Bs[wn + i * 16 + c][g * 8];
#pragma unroll
    for (int mi = 0; mi < 4; mi++)
#pragma unroll
      for (int ni = 0; ni < 4; ni++)
        acc[mi][ni] = __builtin_amdgcn_mfma_f32_16x16x32_bf16(af[mi], bfr[ni], acc[mi][ni], 0, 0, 0);
    __syncthreads();
  }

  if (EPI == 0) {
    const int which = nb >> 12;
    const int h = (nb & 4095) >> 7;
    short* dst = (which == 0) ? Qb : ((which == 1) ? Kb : Vb);
#pragma unroll
    for (int ni = 0; ni < 4; ni++) {
      const int d = wn + ni * 16 + c;
      const float bv = bias[nb + d];
#pragma unroll
      for (int mi = 0; mi < 4; mi++)
#pragma unroll
        for (int j = 0; j < 4; j++) {
          const int row = m0 + wm + mi * 16 + g * 4 + j;
          dst[((size_t)h * S_LEN + row) * HD + d] = f2bf(acc[mi][ni][j] + bv);
        }
    }
  } else {
#pragma unroll
    for (int ni = 0; ni < 4; ni++) {
      const int n = nb + wn + ni * 16 + c;
#pragma unroll
      for (int mi = 0; mi < 4; mi++)
#pragma unroll
        for (int j = 0; j < 4; j++) {
          const int row = m0 + wm + mi * 16 + g * 4 + j;
          Cout[(size_t)row * N + n] = acc[mi][ni][j];
        }
    }
  }
}

// ============ RoPE ============
__global__ void rope_kernel(const int* __restrict__ positions,
                            short* __restrict__ Qb, short* __restrict__ Kb)
{
  const int s = blockIdx.x;
  const int h = blockIdx.y * 4 + threadIdx.y;
  const int d = threadIdx.x;
  const float pos = (float)positions[s];
  const float inv_freq = exp2f(-(float)d * 0.20762050593046014f);
  const float ang = pos * inv_freq;
  float sn, cs;
  sincosf(ang, &sn, &cs);
  const size_t base = ((size_t)h * S_LEN + s) * HD + d;
  const float scale = 0.08838834764831845f;
  float x1 = bf2f(Qb[base]), x2 = bf2f(Qb[base + 64]);
  Qb[base]      = f2bf((x1 * cs - x2 * sn) * scale);
  Qb[base + 64] = f2bf((x2 * cs + x1 * sn) * scale);
  x1 = bf2f(Kb[base]); x2 = bf2f(Kb[base + 64]);
  Kb[base]      = f2bf(x1 * cs - x2 * sn);
  Kb[base + 64] = f2bf(x2 * cs + x1 * sn);
}

// ============ V -> Vt [NH][HD][S] ============
__global__ __launch_bounds__(256)
void vtrans_kernel(const short* __restrict__ V, short* __restrict__ Vt)
{
  __shared__ short tile[64][72];
  const int h = blockIdx.z;
  const int s0 = blockIdx.x * 64;
  const int d0 = blockIdx.y * 64;
  const int tx = threadIdx.x & 63, ty = threadIdx.x >> 6;
  for (int r = ty; r < 64; r += 4)
    tile[r][tx] = V[((size_t)h * S_LEN + s0 + r) * HD + d0 + tx];
  __syncthreads();
  for (int r = ty; r < 64; r += 4)
    Vt[((size_t)h * HD + d0 + r) * S_LEN + s0 + tx] = tile[tx][r];
}

// ============ causal flash attention (LDS-staged K/V, double-buffered) ============
__global__ __launch_bounds__(512)
void attn_kernel(const short* __restrict__ Q, const short* __restrict__ Kg,
                 const short* __restrict__ Vtg, short* __restrict__ attn_out)
{
  __shared__ short Ks[2][32][136];
  __shared__ short Vs[2][128][40];
  __shared__ short Plds[8][16][40];
  const int h = blockIdx.y;
  const int q0 = blockIdx.x * 128;
  const int t = threadIdx.x;
  const int w = t >> 6, lane = t & 63, c = lane & 15, g = lane >> 4;
  const short* Qh = Q   + (size_t)h * S_LEN * HD;
  const short* Kh = Kg  + (size_t)h * S_LEN * HD;
  const short* Vh = Vtg + (size_t)h * HD * S_LEN;

  const int krow = t >> 4, kc16 = t & 15;
  const int vrow = t >> 2, vc16 = t & 3;

  const int qrow = q0 + w * 16 + c;
  s16x8 qf[4];
#pragma unroll
  for (int di = 0; di < 4; di++)
    qf[di] = *(const s16x8*)&Qh[(size_t)qrow * HD + di * 32 + g * 8];

  f32x4 o[8];
#pragma unroll
  for (int dt = 0; dt < 8; dt++) o[dt] = (f32x4){0.f, 0.f, 0.f, 0.f};
  float m_r[4], l_r[4];
#pragma unroll
  for (int j = 0; j < 4; j++) { m_r[j] = -3.0e38f; l_r[j] = 0.f; }

  const int nt = q0 / 32 + 4;

  {
    s16x8 gK = *(const s16x8*)&Kh[(size_t)krow * HD + kc16 * 8];
    s16x8 gV = *(const s16x8*)&Vh[(size_t)vrow * S_LEN + vc16 * 8];
    *(s16x8*)&Ks[0][krow][kc16 * 8] = gK;
    *(s16x8*)&Vs[0][vrow][vc16 * 8] = gV;
  }
  __syncthreads();

  for (int kt = 0; kt < nt; kt++) {
    const int cur = kt & 1;
    const int kb = kt * 32;
    s16x8 gK, gV;
    if (kt + 1 < nt) {
      gK = *(const s16x8*)&Kh[(size_t)(kb + 32 + krow) * HD + kc16 * 8];
      gV = *(const s16x8*)&Vh[(size_t)vrow * S_LEN + kb + 32 + vc16 * 8];
    }
    f32x4 s0 = (f32x4){0.f, 0.f, 0.f, 0.f}, s1 = (f32x4){0.f, 0.f, 0.f, 0.f};
#pragma unroll
    for (int di = 0; di < 4; di++) {
      s16x8 kf0 = *(const s16x8*)&Ks[cur][c][di * 32 + g * 8];
      s16x8 kf1 = *(const s16x8*)&Ks[cur][16 + c][di * 32 + g * 8];
      s0 = __builtin_amdgcn_mfma_f32_16x16x32_bf16(qf[di], kf0, s0, 0, 0, 0);
      s1 = __builtin_amdgcn_mfma_f32_16x16x32_bf16(qf[di], kf1, s1, 0, 0, 0);
    }
    float p0[4], p1[4], alpha[4];
#pragma unroll
    for (int j = 0; j < 4; j++) {
      const int qg = q0 + w * 16 + g * 4 + j;
      const float v0 = (kb + c      <= qg) ? s0[j] : -__builtin_inff();
      const float v1 = (kb + 16 + c <= qg) ? s1[j] : -__builtin_inff();
      float mx = fmaxf(v0, v1);
#pragma unroll
      for (int off = 1; off < 16; off <<= 1) mx = fmaxf(mx, __shfl_xor(mx, off, 64));
      const float mn = fmaxf(m_r[j], mx);
      alpha[j] = __expf(m_r[j] - mn);
      p0[j] = __expf(v0 - mn);
      p1[j] = __expf(v1 - mn);
      float rs = p0[j] + p1[j];
#pragma unroll
      for (int off = 1; off < 16; off <<= 1) rs += __shfl_xor(rs, off, 64);
      l_r[j] = l_r[j] * alpha[j] + rs;
      m_r[j] = mn;
    }
#pragma unroll
    for (int dt = 0; dt < 8; dt++)
#pragma unroll
      for (int j = 0; j < 4; j++) o[dt][j] *= alpha[j];
#pragma unroll
    for (int j = 0; j < 4; j++) {
      Plds[w][g * 4 + j][c]      = f2bf(p0[j]);
      Plds[w][g * 4 + j][16 + c] = f2bf(p1[j]);
    }
    const s16x8 pa = *(const s16x8*)&Plds[w][c][g * 8];
#pragma unroll
    for (int dt = 0; dt < 8; dt++) {
      s16x8 vf = *(const s16x8*)&Vs[cur][dt * 16 + c][g * 8];
      o[dt] = __builtin_amdgcn_mfma_f32_16x16x32_bf16(pa, vf, o[dt], 0, 0, 0);
    }
    __syncthreads();
    if (kt + 1 < nt) {
      *(s16x8*)&Ks[cur ^ 1][krow][kc16 * 8] = gK;
      *(s16x8*)&Vs[cur ^ 1][vrow][vc16 * 8] = gV;
    }
    __syncthreads();
  }

  float inv_l[4];
#pragma unroll
  for (int j = 0; j < 4; j++) inv_l[j] = 1.0f / l_r[j];
#pragma unroll
  for (int dt = 0; dt < 8; dt++)
#pragma unroll
    for (int j = 0; j < 4; j++) {
      const int row = q0 + w * 16 + g * 4 + j;
      attn_out[(size_t)row * HID + h * HD + dt * 16 + c] = f2bf(o[dt][j] * inv_l[j]);
    }
}

extern "C" void kernel_launch(void* const* d_in, const int* in_sizes, int n_in,
                              void* d_out, int out_size, void* d_ws, size_t ws_size,
                              hipStream_t stream)
{
  const int*   positions = (const int*)d_in[0];
  const float* hidden    = (const float*)d_in[1];
  const float* w_qkv     = (const float*)d_in[2];
  const float* b_qkv     = (const float*)d_in[3];
  const float* w_o       = (const float*)d_in[4];
  float* out = (float*)d_out;

  char* ws = (char*)d_ws;
  const size_t MB = (size_t)1 << 20;

  if (ws_size >= 224 * MB) {
    short* Ah    = (short*)(ws);                 // 16 MB  bf16 [S][KD]
    short* Wqt   = (short*)(ws + 16 * MB);       // 96 MB  bf16 [3*HID][KD]
    short* Wot   = (short*)(ws + 112 * MB);      // 32 MB  bf16 [HID][KD]
    short* Qb    = (short*)(ws + 144 * MB);      // 16 MB
    short* Kb    = (short*)(ws + 160 * MB);      // 16 MB
    short* Vb    = (short*)(ws + 176 * MB);      // 16 MB
    short* Vt    = (short*)(ws + 192 * MB);      // 16 MB
    short* attnb = (short*)(ws + 208 * MB);      // 16 MB  bf16 [S][HID]

    cvt_kernel<<<4096, 256, 0, stream>>>(hidden, Ah);
    transcvt_kernel<<<dim3(KD / 64, 3 * HID / 64), 256, 0, stream>>>(w_qkv, Wqt, 3 * HID);
    transcvt_kernel<<<dim3(KD / 64, HID / 64), 256, 0, stream>>>(w_o, Wot, HID);
    gemm3_kernel<<<384, 512, 0, stream>>>(Ah, Wqt, b_qkv, Qb, Kb, Vb);
    rope_kernel<<<dim3(S_LEN, NH / 4), dim3(64, 4), 0, stream>>>(positions, Qb, Kb);
    vtrans_kernel<<<dim3(S_LEN / 64, HD / 64, NH), 256, 0, stream>>>(Vb, Vt);
    attn_kernel<<<dim3(S_LEN / 128, NH), 512, 0, stream>>>(Qb, Kb, Vt, attnb);
    gemm2_kernel<1><<<dim3(16, 32), 256, 0, stream>>>(attnb, Wot, nullptr, HID,
                                                      nullptr, nullptr, nullptr, out);
  } else {
    short* Qb    = (short*)(ws);
    short* Kb    = (short*)(ws + 16 * MB);
    short* Vb    = (short*)(ws + 32 * MB);
    short* Vt    = (short*)(ws + 48 * MB);
    short* attnb = (short*)(ws + 64 * MB);

    gemm_kernel<0, 0><<<dim3(16, 96), 256, 0, stream>>>(hidden, w_qkv, b_qkv, 3 * HID,
                                                        Qb, Kb, Vb, nullptr);
    rope_kernel<<<dim3(S_LEN, NH / 4), dim3(64, 4), 0, stream>>>(positions, Qb, Kb);
    vtrans_kernel<<<dim3(S_LEN / 64, HD / 64, NH), 256, 0, stream>>>(Vb, Vt);
    attn_kernel<<<dim3(S_LEN / 128, NH), 512, 0, stream>>>(Qb, Kb, Vt, attnb);
    gemm_kernel<1, 1><<<dim3(16, 32), 256, 0, stream>>>(attnb, w_o, nullptr, HID,
                                                        nullptr, nullptr, nullptr, out);
  }
}

// Round 5
// 585.419 us; speedup vs baseline: 1.9814x; 1.0657x over previous
//
#include <hip/hip_runtime.h>
#include <hip/hip_bf16.h>

#define S_LEN 2048
#define HID   4096
#define NH    32
#define HD    128
#define KD    4096

typedef __attribute__((ext_vector_type(4))) float f32x4;
typedef __attribute__((ext_vector_type(8))) short s16x8;
typedef __attribute__((ext_vector_type(4))) short s16x4;

#define AS1 __attribute__((address_space(1)))
#define AS3 __attribute__((address_space(3)))

__device__ __forceinline__ void gl_lds16(const void* g, void* l) {
  __builtin_amdgcn_global_load_lds((const AS1 void*)g, (AS3 void*)l, 16, 0, 0);
}

__device__ inline short f2bf(float f) {
  union { float f; unsigned u; } v; v.f = f;
  return (short)((v.u + 0x7fffu + ((v.u >> 16) & 1u)) >> 16);
}
__device__ inline float bf2f(short s) {
  union { unsigned u; float f; } v; v.u = ((unsigned)(unsigned short)s) << 16;
  return v.f;
}

// ============ one-time converts ============
__global__ __launch_bounds__(256)
void cvt_kernel(const float* __restrict__ A, short* __restrict__ Ab) {
  const size_t i = ((size_t)blockIdx.x * 256 + threadIdx.x) * 8;
  f32x4 v0 = *(const f32x4*)&A[i];
  f32x4 v1 = *(const f32x4*)&A[i + 4];
  s16x8 r;
  r[0]=f2bf(v0[0]); r[1]=f2bf(v0[1]); r[2]=f2bf(v0[2]); r[3]=f2bf(v0[3]);
  r[4]=f2bf(v1[0]); r[5]=f2bf(v1[1]); r[6]=f2bf(v1[2]); r[7]=f2bf(v1[3]);
  *(s16x8*)&Ab[i] = r;
}

// W [KD][N] f32 -> Wt [N][KD] bf16
__global__ __launch_bounds__(256)
void transcvt_kernel(const float* __restrict__ W, short* __restrict__ Wt, const int N) {
  __shared__ float tile[64][65];
  const int k0 = blockIdx.x * 64, n0 = blockIdx.y * 64;
  const int t = threadIdx.x;
#pragma unroll
  for (int i = 0; i < 16; ++i) {
    const int e = i * 256 + t;
    const int k = e >> 6, n = e & 63;
    tile[n][k] = W[(size_t)(k0 + k) * N + n0 + n];
  }
  __syncthreads();
  const int nn = t >> 2, ks = (t & 3) * 16;
  s16x8 a, b;
#pragma unroll
  for (int i = 0; i < 8; i++) a[i] = f2bf(tile[nn][ks + i]);
#pragma unroll
  for (int i = 0; i < 8; i++) b[i] = f2bf(tile[nn][ks + 8 + i]);
  *(s16x8*)&Wt[(size_t)(n0 + nn) * KD + k0 + ks]     = a;
  *(s16x8*)&Wt[(size_t)(n0 + nn) * KD + k0 + ks + 8] = b;
}

// ============ gemm4: BM=256 BN=128 BK=64(k-halved), 8 waves 4Mx2N, counted vmcnt ============
// A bf16 [M][KD], Bt bf16 [N][KD].
// EPI 0: M=2048 N=12288, 768 blocks, +bias, bf16 scatter to Q/K/V head-major.
// EPI 1: M=2048 N=4096,  256 blocks, f32 Cout.
// LDS buf (48KB): A region [khalf s][256 rows][64B] at s*16384; B region at 32768 + s*8192.
// Swizzle: byte ^= ((row&14)>>1)<<4 == la ^ (((la>>7)&7)<<4)  (involution, bits 4-6 from row bits 1-3).
template<int EPI>
__global__ __launch_bounds__(512, 2)
void gemm4_kernel(const short* __restrict__ A, const short* __restrict__ Bt,
                  const float* __restrict__ bias,
                  short* __restrict__ Qb, short* __restrict__ Kb, short* __restrict__ Vb,
                  float* __restrict__ Cout)
{
  __shared__ char sm[2][49152] __attribute__((aligned(128)));
  const int bid = blockIdx.x;
  const int xcd = bid & 7, idx = bid >> 3;
  const int m0 = (idx & 7) * 256;
  const int n0 = (xcd * ((EPI == 0) ? 12 : 4) + (idx >> 3)) * 128;

  const int t = threadIdx.x, lane = t & 63, c = lane & 15, g = lane >> 4;
  const int w = t >> 6, wr = w >> 1, wc = w & 1;
  const int flip = ((c >> 1) & 7) << 4;
  // ds_read lane bases: addr = buf + [A: s*16384 + laneA + mi*1024 | B: 32768 + s*8192 + laneB + ni*1024]
  const int laneA = (wr * 4096 + c * 64 + g * 16) ^ flip;
  const int laneB = (wc * 4096 + c * 64 + g * 16) ^ flip;

  // pre-swizzled staging sources: LDS[la] must hold G[swz(la)]
  const char* srcA[2][2];
  const char* srcB[2];
#pragma unroll
  for (int s = 0; s < 2; ++s) {
#pragma unroll
    for (int j = 0; j < 2; ++j) {
      int la = s * 16384 + j * 8192 + t * 16;
      int ls = la ^ ((la >> 3) & 0x70);
      srcA[s][j] = (const char*)A + (size_t)(m0 + ((ls >> 6) & 255)) * (KD * 2)
                   + (ls >> 14) * 64 + (ls & 63);
    }
    int la = s * 8192 + t * 16;
    int ls = la ^ ((la >> 3) & 0x70);
    srcB[s] = (const char*)Bt + (size_t)(n0 + ((ls >> 6) & 127)) * (KD * 2)
              + (ls >> 13) * 64 + (ls & 63);
  }

  f32x4 acc[4][4];
#pragma unroll
  for (int i = 0; i < 4; i++)
#pragma unroll
    for (int j = 0; j < 4; j++) acc[i][j] = (f32x4){0.f, 0.f, 0.f, 0.f};

  // stage k-half S of K-tile KT into buffer NB (3 gl_lds per thread)
#define STG(NB, S, KT) do {                                               \
    const size_t ko_ = (size_t)(KT) * 128;                                \
    gl_lds16(srcA[S][0] + ko_, sm[NB] + (S) * 16384 + t * 16);            \
    gl_lds16(srcA[S][1] + ko_, sm[NB] + (S) * 16384 + 8192 + t * 16);     \
    gl_lds16(srcB[S] + ko_,    sm[NB] + 32768 + (S) * 8192 + t * 16);     \
  } while (0)

  // super-phase: compute k-half S of tile in buf CB; optionally stage (NB,S,KT); counted wait WN
#define SP(CB, NB, S, KT, DOSTAGE, WN) do {                               \
    if (DOSTAGE) STG(NB, S, KT);                                          \
    const char* b_ = sm[CB];                                              \
    s16x8 a0 = *(const s16x8*)(b_ + (S) * 16384 + laneA);                 \
    s16x8 a1 = *(const s16x8*)(b_ + (S) * 16384 + laneA + 1024);          \
    s16x8 a2 = *(const s16x8*)(b_ + (S) * 16384 + laneA + 2048);          \
    s16x8 a3 = *(const s16x8*)(b_ + (S) * 16384 + laneA + 3072);          \
    s16x8 b0 = *(const s16x8*)(b_ + 32768 + (S) * 8192 + laneB);          \
    s16x8 b1 = *(const s16x8*)(b_ + 32768 + (S) * 8192 + laneB + 1024);   \
    s16x8 b2 = *(const s16x8*)(b_ + 32768 + (S) * 8192 + laneB + 2048);   \
    s16x8 b3 = *(const s16x8*)(b_ + 32768 + (S) * 8192 + laneB + 3072);   \
    __builtin_amdgcn_s_setprio(1);                                        \
    acc[0][0] = __builtin_amdgcn_mfma_f32_16x16x32_bf16(a0, b0, acc[0][0], 0, 0, 0); \
    acc[0][1] = __builtin_amdgcn_mfma_f32_16x16x32_bf16(a0, b1, acc[0][1], 0, 0, 0); \
    acc[0][2] = __builtin_amdgcn_mfma_f32_16x16x32_bf16(a0, b2, acc[0][2], 0, 0, 0); \
    acc[0][3] = __builtin_amdgcn_mfma_f32_16x16x32_bf16(a0, b3, acc[0][3], 0, 0, 0); \
    acc[1][0] = __builtin_amdgcn_mfma_f32_16x16x32_bf16(a1, b0, acc[1][0], 0, 0, 0); \
    acc[1][1] = __builtin_amdgcn_mfma_f32_16x16x32_bf16(a1, b1, acc[1][1], 0, 0, 0); \
    acc[1][2] = __builtin_amdgcn_mfma_f32_16x16x32_bf16(a1, b2, acc[1][2], 0, 0, 0); \
    acc[1][3] = __builtin_amdgcn_mfma_f32_16x16x32_bf16(a1, b3, acc[1][3], 0, 0, 0); \
    acc[2][0] = __builtin_amdgcn_mfma_f32_16x16x32_bf16(a2, b0, acc[2][0], 0, 0, 0); \
    acc[2][1] = __builtin_amdgcn_mfma_f32_16x16x32_bf16(a2, b1, acc[2][1], 0, 0, 0); \
    acc[2][2] = __builtin_amdgcn_mfma_f32_16x16x32_bf16(a2, b2, acc[2][2], 0, 0, 0); \
    acc[2][3] = __builtin_amdgcn_mfma_f32_16x16x32_bf16(a2, b3, acc[2][3], 0, 0, 0); \
    acc[3][0] = __builtin_amdgcn_mfma_f32_16x16x32_bf16(a3, b0, acc[3][0], 0, 0, 0); \
    acc[3][1] = __builtin_amdgcn_mfma_f32_16x16x32_bf16(a3, b1, acc[3][1], 0, 0, 0); \
    acc[3][2] = __builtin_amdgcn_mfma_f32_16x16x32_bf16(a3, b2, acc[3][2], 0, 0, 0); \
    acc[3][3] = __builtin_amdgcn_mfma_f32_16x16x32_bf16(a3, b3, acc[3][3], 0, 0, 0); \
    __builtin_amdgcn_s_setprio(0);                                        \
    asm volatile("s_waitcnt vmcnt(" #WN ")" ::: "memory");                \
    __builtin_amdgcn_s_barrier();                                         \
  } while (0)

  // prologue: tile 0 fully staged into buf0; confirm k-half0 (k-half1 may fly)
  STG(0, 0, 0);
  STG(0, 1, 0);
  asm volatile("s_waitcnt vmcnt(3)" ::: "memory");
  __builtin_amdgcn_s_barrier();

  for (int i = 0; i < 31; ++i) {
    const int t0 = 2 * i;
    SP(0, 1, 0, t0 + 1, true, 3);   // tile t0 (buf0), kh0; stage t0+1 kh0 -> buf1
    SP(0, 1, 1, t0 + 1, true, 3);   // tile t0, kh1;      stage t0+1 kh1
    SP(1, 0, 0, t0 + 2, true, 3);   // tile t0+1 (buf1);  stage t0+2 kh0 -> buf0
    SP(1, 0, 1, t0 + 2, true, 3);
  }
  SP(0, 1, 0, 63, true, 3);         // tile 62, stage 63 -> buf1
  SP(0, 1, 1, 63, true, 3);
  SP(1, 0, 0, 0, false, 0);         // tile 63: no stage; vmcnt(0) confirms its kh1
  SP(1, 0, 1, 0, false, 0);

#undef STG
#undef SP

  // ---- epilogue ----
  if (EPI == 0) {
#pragma unroll
    for (int ni = 0; ni < 4; ++ni) {
      const int ncol = n0 + wc * 64 + ni * 16 + c;
      const int which = ncol >> 12;
      const int h = (ncol >> 7) & 31;
      const int dcl = ncol & 127;
      short* dst = (which == 0) ? Qb : ((which == 1) ? Kb : Vb);
      const float bv = bias[ncol];
#pragma unroll
      for (int mi = 0; mi < 4; ++mi)
#pragma unroll
        for (int jj = 0; jj < 4; ++jj) {
          const int row = m0 + wr * 64 + mi * 16 + g * 4 + jj;
          dst[((size_t)h * S_LEN + row) * HD + dcl] = f2bf(acc[mi][ni][jj] + bv);
        }
    }
  } else {
#pragma unroll
    for (int ni = 0; ni < 4; ++ni) {
      const int ncol = n0 + wc * 64 + ni * 16 + c;
#pragma unroll
      for (int mi = 0; mi < 4; ++mi)
#pragma unroll
        for (int jj = 0; jj < 4; ++jj) {
          const int row = m0 + wr * 64 + mi * 16 + g * 4 + jj;
          Cout[(size_t)row * HID + ncol] = acc[mi][ni][jj];
        }
    }
  }
}

// ============ fallback GEMM (reg-staged) ============
template<int EPI, int ABF16>
__global__ __launch_bounds__(256)
void gemm_kernel(const void* __restrict__ Av, const float* __restrict__ B,
                 const float* __restrict__ bias, const int N,
                 short* __restrict__ Qb, short* __restrict__ Kb, short* __restrict__ Vb,
                 float* __restrict__ Cout)
{
  __shared__ short As[128][40];
  __shared__ short Bs[128][40];
  const int m0 = blockIdx.x * 128;
  const int nb = blockIdx.y * 128;
  const int t  = threadIdx.x;
  const int w = t >> 6, lane = t & 63, c = lane & 15, g = lane >> 4;
  const int wm = (w >> 1) * 64, wn = (w & 1) * 64;

  f32x4 acc[4][4];
#pragma unroll
  for (int i = 0; i < 4; i++)
#pragma unroll
    for (int j = 0; j < 4; j++) acc[i][j] = (f32x4){0.f, 0.f, 0.f, 0.f};

  const int ar = t >> 3;
  const int ac = (t & 7) * 4;
  const int bn = t & 127;
  const int bkq = (t >> 7) * 16;

  for (int k0 = 0; k0 < KD; k0 += 32) {
#pragma unroll
    for (int rr = 0; rr < 4; rr++) {
      const int row = rr * 32 + ar;
      if (ABF16) {
        *(s16x4*)&As[row][ac] =
          *(const s16x4*)((const short*)Av + (size_t)(m0 + row) * KD + k0 + ac);
      } else {
        f32x4 v = *(const f32x4*)((const float*)Av + (size_t)(m0 + row) * KD + k0 + ac);
        s16x4 pk;
        pk[0] = f2bf(v[0]); pk[1] = f2bf(v[1]); pk[2] = f2bf(v[2]); pk[3] = f2bf(v[3]);
        *(s16x4*)&As[row][ac] = pk;
      }
    }
    const float* pB = B + (size_t)(k0 + bkq) * N + nb + bn;
    s16x8 b0, b1;
#pragma unroll
    for (int i = 0; i < 8; i++) b0[i] = f2bf(pB[(size_t)i * N]);
#pragma unroll
    for (int i = 0; i < 8; i++) b1[i] = f2bf(pB[(size_t)(i + 8) * N]);
    *(s16x8*)&Bs[bn][bkq]     = b0;
    *(s16x8*)&Bs[bn][bkq + 8] = b1;
    __syncthreads();
    s16x8 af[4], bfr[4];
#pragma unroll
    for (int i = 0; i < 4; i++) af[i]  = *(const s16x8*)&As[wm + i * 16 + c][g * 8];
#pragma unroll
    for (int i = 0; i < 4; i++) bfr[i] = *(const s16x8*)&Bs[wn + i * 16 + c][g * 8];
#pragma unroll
    for (int mi = 0; mi < 4; mi++)
#pragma unroll
      for (int ni = 0; ni < 4; ni++)
        acc[mi][ni] = __builtin_amdgcn_mfma_f32_16x16x32_bf16(af[mi], bfr[ni], acc[mi][ni], 0, 0, 0);
    __syncthreads();
  }

  if (EPI == 0) {
    const int which = nb >> 12;
    const int h = (nb & 4095) >> 7;
    short* dst = (which == 0) ? Qb : ((which == 1) ? Kb : Vb);
#pragma unroll
    for (int ni = 0; ni < 4; ni++) {
      const int d = wn + ni * 16 + c;
      const float bv = bias[nb + d];
#pragma unroll
      for (int mi = 0; mi < 4; mi++)
#pragma unroll
        for (int j = 0; j < 4; j++) {
          const int row = m0 + wm + mi * 16 + g * 4 + j;
          dst[((size_t)h * S_LEN + row) * HD + d] = f2bf(acc[mi][ni][j] + bv);
        }
    }
  } else {
#pragma unroll
    for (int ni = 0; ni < 4; ni++) {
      const int n = nb + wn + ni * 16 + c;
#pragma unroll
      for (int mi = 0; mi < 4; mi++)
#pragma unroll
        for (int j = 0; j < 4; j++) {
          const int row = m0 + wm + mi * 16 + g * 4 + j;
          Cout[(size_t)row * N + n] = acc[mi][ni][j];
        }
    }
  }
}

// ============ RoPE ============
__global__ void rope_kernel(const int* __restrict__ positions,
                            short* __restrict__ Qb, short* __restrict__ Kb)
{
  const int s = blockIdx.x;
  const int h = blockIdx.y * 4 + threadIdx.y;
  const int d = threadIdx.x;
  const float pos = (float)positions[s];
  const float inv_freq = exp2f(-(float)d * 0.20762050593046014f);
  const float ang = pos * inv_freq;
  float sn, cs;
  sincosf(ang, &sn, &cs);
  const size_t base = ((size_t)h * S_LEN + s) * HD + d;
  const float scale = 0.08838834764831845f;
  float x1 = bf2f(Qb[base]), x2 = bf2f(Qb[base + 64]);
  Qb[base]      = f2bf((x1 * cs - x2 * sn) * scale);
  Qb[base + 64] = f2bf((x2 * cs + x1 * sn) * scale);
  x1 = bf2f(Kb[base]); x2 = bf2f(Kb[base + 64]);
  Kb[base]      = f2bf(x1 * cs - x2 * sn);
  Kb[base + 64] = f2bf(x2 * cs + x1 * sn);
}

// ============ V -> Vt [NH][HD][S] ============
__global__ __launch_bounds__(256)
void vtrans_kernel(const short* __restrict__ V, short* __restrict__ Vt)
{
  __shared__ short tile[64][72];
  const int h = blockIdx.z;
  const int s0 = blockIdx.x * 64;
  const int d0 = blockIdx.y * 64;
  const int tx = threadIdx.x & 63, ty = threadIdx.x >> 6;
  for (int r = ty; r < 64; r += 4)
    tile[r][tx] = V[((size_t)h * S_LEN + s0 + r) * HD + d0 + tx];
  __syncthreads();
  for (int r = ty; r < 64; r += 4)
    Vt[((size_t)h * HD + d0 + r) * S_LEN + s0 + tx] = tile[tx][r];
}

// ============ causal flash attention (LDS-staged K/V, double-buffered) ============
__global__ __launch_bounds__(512)
void attn_kernel(const short* __restrict__ Q, const short* __restrict__ Kg,
                 const short* __restrict__ Vtg, short* __restrict__ attn_out)
{
  __shared__ short Ks[2][32][136];
  __shared__ short Vs[2][128][40];
  __shared__ short Plds[8][16][40];
  const int h = blockIdx.y;
  const int q0 = blockIdx.x * 128;
  const int t = threadIdx.x;
  const int w = t >> 6, lane = t & 63, c = lane & 15, g = lane >> 4;
  const short* Qh = Q   + (size_t)h * S_LEN * HD;
  const short* Kh = Kg  + (size_t)h * S_LEN * HD;
  const short* Vh = Vtg + (size_t)h * HD * S_LEN;

  const int krow = t >> 4, kc16 = t & 15;
  const int vrow = t >> 2, vc16 = t & 3;

  const int qrow = q0 + w * 16 + c;
  s16x8 qf[4];
#pragma unroll
  for (int di = 0; di < 4; di++)
    qf[di] = *(const s16x8*)&Qh[(size_t)qrow * HD + di * 32 + g * 8];

  f32x4 o[8];
#pragma unroll
  for (int dt = 0; dt < 8; dt++) o[dt] = (f32x4){0.f, 0.f, 0.f, 0.f};
  float m_r[4], l_r[4];
#pragma unroll
  for (int j = 0; j < 4; j++) { m_r[j] = -3.0e38f; l_r[j] = 0.f; }

  const int nt = q0 / 32 + 4;

  {
    s16x8 gK = *(const s16x8*)&Kh[(size_t)krow * HD + kc16 * 8];
    s16x8 gV = *(const s16x8*)&Vh[(size_t)vrow * S_LEN + vc16 * 8];
    *(s16x8*)&Ks[0][krow][kc16 * 8] = gK;
    *(s16x8*)&Vs[0][vrow][vc16 * 8] = gV;
  }
  __syncthreads();

  for (int kt = 0; kt < nt; kt++) {
    const int cur = kt & 1;
    const int kb = kt * 32;
    s16x8 gK, gV;
    if (kt + 1 < nt) {
      gK = *(const s16x8*)&Kh[(size_t)(kb + 32 + krow) * HD + kc16 * 8];
      gV = *(const s16x8*)&Vh[(size_t)vrow * S_LEN + kb + 32 + vc16 * 8];
    }
    f32x4 s0 = (f32x4){0.f, 0.f, 0.f, 0.f}, s1 = (f32x4){0.f, 0.f, 0.f, 0.f};
#pragma unroll
    for (int di = 0; di < 4; di++) {
      s16x8 kf0 = *(const s16x8*)&Ks[cur][c][di * 32 + g * 8];
      s16x8 kf1 = *(const s16x8*)&Ks[cur][16 + c][di * 32 + g * 8];
      s0 = __builtin_amdgcn_mfma_f32_16x16x32_bf16(qf[di], kf0, s0, 0, 0, 0);
      s1 = __builtin_amdgcn_mfma_f32_16x16x32_bf16(qf[di], kf1, s1, 0, 0, 0);
    }
    float p0[4], p1[4], alpha[4];
#pragma unroll
    for (int j = 0; j < 4; j++) {
      const int qg = q0 + w * 16 + g * 4 + j;
      const float v0 = (kb + c      <= qg) ? s0[j] : -__builtin_inff();
      const float v1 = (kb + 16 + c <= qg) ? s1[j] : -__builtin_inff();
      float mx = fmaxf(v0, v1);
#pragma unroll
      for (int off = 1; off < 16; off <<= 1) mx = fmaxf(mx, __shfl_xor(mx, off, 64));
      const float mn = fmaxf(m_r[j], mx);
      alpha[j] = __expf(m_r[j] - mn);
      p0[j] = __expf(v0 - mn);
      p1[j] = __expf(v1 - mn);
      float rs = p0[j] + p1[j];
#pragma unroll
      for (int off = 1; off < 16; off <<= 1) rs += __shfl_xor(rs, off, 64);
      l_r[j] = l_r[j] * alpha[j] + rs;
      m_r[j] = mn;
    }
#pragma unroll
    for (int dt = 0; dt < 8; dt++)
#pragma unroll
      for (int j = 0; j < 4; j++) o[dt][j] *= alpha[j];
#pragma unroll
    for (int j = 0; j < 4; j++) {
      Plds[w][g * 4 + j][c]      = f2bf(p0[j]);
      Plds[w][g * 4 + j][16 + c] = f2bf(p1[j]);
    }
    const s16x8 pa = *(const s16x8*)&Plds[w][c][g * 8];
#pragma unroll
    for (int dt = 0; dt < 8; dt++) {
      s16x8 vf = *(const s16x8*)&Vs[cur][dt * 16 + c][g * 8];
      o[dt] = __builtin_amdgcn_mfma_f32_16x16x32_bf16(pa, vf, o[dt], 0, 0, 0);
    }
    __syncthreads();
    if (kt + 1 < nt) {
      *(s16x8*)&Ks[cur ^ 1][krow][kc16 * 8] = gK;
      *(s16x8*)&Vs[cur ^ 1][vrow][vc16 * 8] = gV;
    }
    __syncthreads();
  }

  float inv_l[4];
#pragma unroll
  for (int j = 0; j < 4; j++) inv_l[j] = 1.0f / l_r[j];
#pragma unroll
  for (int dt = 0; dt < 8; dt++)
#pragma unroll
    for (int j = 0; j < 4; j++) {
      const int row = q0 + w * 16 + g * 4 + j;
      attn_out[(size_t)row * HID + h * HD + dt * 16 + c] = f2bf(o[dt][j] * inv_l[j]);
    }
}

extern "C" void kernel_launch(void* const* d_in, const int* in_sizes, int n_in,
                              void* d_out, int out_size, void* d_ws, size_t ws_size,
                              hipStream_t stream)
{
  const int*   positions = (const int*)d_in[0];
  const float* hidden    = (const float*)d_in[1];
  const float* w_qkv     = (const float*)d_in[2];
  const float* b_qkv     = (const float*)d_in[3];
  const float* w_o       = (const float*)d_in[4];
  float* out = (float*)d_out;

  char* ws = (char*)d_ws;
  const size_t MB = (size_t)1 << 20;

  if (ws_size >= 224 * MB) {
    short* Ah    = (short*)(ws);                 // 16 MB  bf16 [S][KD]
    short* Wqt   = (short*)(ws + 16 * MB);       // 96 MB  bf16 [3*HID][KD]
    short* Wot   = (short*)(ws + 112 * MB);      // 32 MB  bf16 [HID][KD]
    short* Qb    = (short*)(ws + 144 * MB);      // 16 MB
    short* Kb    = (short*)(ws + 160 * MB);      // 16 MB
    short* Vb    = (short*)(ws + 176 * MB);      // 16 MB
    short* Vt    = (short*)(ws + 192 * MB);      // 16 MB
    short* attnb = (short*)(ws + 208 * MB);      // 16 MB  bf16 [S][HID]

    cvt_kernel<<<4096, 256, 0, stream>>>(hidden, Ah);
    transcvt_kernel<<<dim3(KD / 64, 3 * HID / 64), 256, 0, stream>>>(w_qkv, Wqt, 3 * HID);
    transcvt_kernel<<<dim3(KD / 64, HID / 64), 256, 0, stream>>>(w_o, Wot, HID);
    gemm4_kernel<0><<<768, 512, 0, stream>>>(Ah, Wqt, b_qkv, Qb, Kb, Vb, nullptr);
    rope_kernel<<<dim3(S_LEN, NH / 4), dim3(64, 4), 0, stream>>>(positions, Qb, Kb);
    vtrans_kernel<<<dim3(S_LEN / 64, HD / 64, NH), 256, 0, stream>>>(Vb, Vt);
    attn_kernel<<<dim3(S_LEN / 128, NH), 512, 0, stream>>>(Qb, Kb, Vt, attnb);
    gemm4_kernel<1><<<256, 512, 0, stream>>>(attnb, Wot, nullptr,
                                             nullptr, nullptr, nullptr, out);
  } else {
    short* Qb    = (short*)(ws);
    short* Kb    = (short*)(ws + 16 * MB);
    short* Vb    = (short*)(ws + 32 * MB);
    short* Vt    = (short*)(ws + 48 * MB);
    short* attnb = (short*)(ws + 64 * MB);

    gemm_kernel<0, 0><<<dim3(16, 96), 256, 0, stream>>>(hidden, w_qkv, b_qkv, 3 * HID,
                                                        Qb, Kb, Vb, nullptr);
    rope_kernel<<<dim3(S_LEN, NH / 4), dim3(64, 4), 0, stream>>>(positions, Qb, Kb);
    vtrans_kernel<<<dim3(S_LEN / 64, HD / 64, NH), 256, 0, stream>>>(Vb, Vt);
    attn_kernel<<<dim3(S_LEN / 128, NH), 512, 0, stream>>>(Qb, Kb, Vt, attnb);
    gemm_kernel<1, 1><<<dim3(16, 32), 256, 0, stream>>>(attnb, w_o, nullptr, HID,
                                                        nullptr, nullptr, nullptr, out);
  }
}

// Round 6
// 565.050 us; speedup vs baseline: 2.0528x; 1.0360x over previous
//
#include <hip/hip_runtime.h>
#include <hip/hip_bf16.h>

#define S_LEN 2048
#define HID   4096
#define NH    32
#define HD    128
#define KD    4096

typedef __attribute__((ext_vector_type(4))) float f32x4;
typedef __attribute__((ext_vector_type(8))) short s16x8;
typedef __attribute__((ext_vector_type(4))) short s16x4;

#define AS1 __attribute__((address_space(1)))
#define AS3 __attribute__((address_space(3)))

__device__ __forceinline__ void gl_lds16(const void* g, void* l) {
  __builtin_amdgcn_global_load_lds((const AS1 void*)g, (AS3 void*)l, 16, 0, 0);
}

__device__ inline short f2bf(float f) {
  union { float f; unsigned u; } v; v.f = f;
  return (short)((v.u + 0x7fffu + ((v.u >> 16) & 1u)) >> 16);
}
__device__ inline float bf2f(short s) {
  union { unsigned u; float f; } v; v.u = ((unsigned)(unsigned short)s) << 16;
  return v.f;
}

// ============ one-time converts ============
__global__ __launch_bounds__(256)
void cvt_kernel(const float* __restrict__ A, short* __restrict__ Ab) {
  const size_t i = ((size_t)blockIdx.x * 256 + threadIdx.x) * 8;
  f32x4 v0 = *(const f32x4*)&A[i];
  f32x4 v1 = *(const f32x4*)&A[i + 4];
  s16x8 r;
  r[0]=f2bf(v0[0]); r[1]=f2bf(v0[1]); r[2]=f2bf(v0[2]); r[3]=f2bf(v0[3]);
  r[4]=f2bf(v1[0]); r[5]=f2bf(v1[1]); r[6]=f2bf(v1[2]); r[7]=f2bf(v1[3]);
  *(s16x8*)&Ab[i] = r;
}

// W [KD][N] f32 -> Wt [N][KD] bf16
__global__ __launch_bounds__(256)
void transcvt_kernel(const float* __restrict__ W, short* __restrict__ Wt, const int N) {
  __shared__ float tile[64][65];
  const int k0 = blockIdx.x * 64, n0 = blockIdx.y * 64;
  const int t = threadIdx.x;
#pragma unroll
  for (int i = 0; i < 16; ++i) {
    const int e = i * 256 + t;
    const int k = e >> 6, n = e & 63;
    tile[n][k] = W[(size_t)(k0 + k) * N + n0 + n];
  }
  __syncthreads();
  const int nn = t >> 2, ks = (t & 3) * 16;
  s16x8 a, b;
#pragma unroll
  for (int i = 0; i < 8; i++) a[i] = f2bf(tile[nn][ks + i]);
#pragma unroll
  for (int i = 0; i < 8; i++) b[i] = f2bf(tile[nn][ks + 8 + i]);
  *(s16x8*)&Wt[(size_t)(n0 + nn) * KD + k0 + ks]     = a;
  *(s16x8*)&Wt[(size_t)(n0 + nn) * KD + k0 + ks + 8] = b;
}

// ============ gemm5: BM=256 BN=128, 4 waves (2Mx2N), wave-tile 128x64, ============
// 3-deep ring of K=32 half-tiles (24KB each), counted vmcnt, XOR-swizzled LDS.
// A bf16 [M][KD], Bt bf16 [N][KD].
// EPI 0: N=12288, 768 blocks (=3 rounds), +bias, bf16 scatter to Q/K/V head-major.
// EPI 1: N=4096, 256 blocks (=1 round), f32 Cout.
// Slot layout (24KB): A [256 rows][64B] at +0 (16KB); B [128 rows][64B] at +16384 (8KB).
// Swizzle: byte ^= bits[9:7]<<4 (row bits 1-3 -> byte bits 4-6), involution.
template<int EPI>
__global__ __launch_bounds__(256, 2)
void gemm5_kernel(const short* __restrict__ A, const short* __restrict__ Bt,
                  const float* __restrict__ bias,
                  short* __restrict__ Qb, short* __restrict__ Kb, short* __restrict__ Vb,
                  float* __restrict__ Cout)
{
  __shared__ char sm[3][24576] __attribute__((aligned(128)));
  const int KD2 = KD * 2;
  const int bid = blockIdx.x;
  const int xcd = bid & 7, idx = bid >> 3;
  const int m0 = (idx & 7) * 256;
  const int n0 = (xcd * ((EPI == 0) ? 12 : 4) + (idx >> 3)) * 128;

  const int t = threadIdx.x, lane = t & 63, c = lane & 15, g = lane >> 4;
  const int w = t >> 6, wr = w >> 1, wc = w & 1;
  const int flip = ((c >> 1) & 7) << 4;
  const int laneA = wr * 8192 + ((c * 64 + g * 16) ^ flip);
  const int laneB = 16384 + wc * 4096 + ((c * 64 + g * 16) ^ flip);

  // pre-swizzled staging sources: LDS[la] holds G[swz(la)]
  const char* srcA[4];
  const char* srcB[2];
#pragma unroll
  for (int j = 0; j < 4; ++j) {
    const int la = j * 4096 + t * 16;
    const int ls = la ^ ((la >> 3) & 0x70);
    srcA[j] = (const char*)A + (size_t)(m0 + (ls >> 6)) * KD2 + (ls & 63);
  }
#pragma unroll
  for (int j = 0; j < 2; ++j) {
    const int la = j * 4096 + t * 16;
    const int ls = la ^ ((la >> 3) & 0x70);
    srcB[j] = (const char*)Bt + (size_t)(n0 + (ls >> 6)) * KD2 + (ls & 63);
  }

  f32x4 acc[8][4];
#pragma unroll
  for (int i = 0; i < 8; i++)
#pragma unroll
    for (int j = 0; j < 4; j++) acc[i][j] = (f32x4){0.f, 0.f, 0.f, 0.f};

#define STG(S, H) do {                                        \
    const size_t ko_ = (size_t)(H) * 64;                      \
    gl_lds16(srcA[0] + ko_, sm[S] + t * 16);                  \
    gl_lds16(srcA[1] + ko_, sm[S] + 4096  + t * 16);          \
    gl_lds16(srcA[2] + ko_, sm[S] + 8192  + t * 16);          \
    gl_lds16(srcA[3] + ko_, sm[S] + 12288 + t * 16);          \
    gl_lds16(srcB[0] + ko_, sm[S] + 16384 + t * 16);          \
    gl_lds16(srcB[1] + ko_, sm[S] + 20480 + t * 16);          \
  } while (0)

#define COMP(S) do {                                                       \
    const char* b_ = sm[S];                                                \
    s16x8 a_[8], bb_[4];                                                   \
    _Pragma("unroll")                                                      \
    for (int mi = 0; mi < 8; ++mi) a_[mi] = *(const s16x8*)(b_ + laneA + mi * 1024); \
    _Pragma("unroll")                                                      \
    for (int ni = 0; ni < 4; ++ni) bb_[ni] = *(const s16x8*)(b_ + laneB + ni * 1024); \
    __builtin_amdgcn_s_setprio(1);                                         \
    _Pragma("unroll")                                                      \
    for (int mi = 0; mi < 8; ++mi)                                         \
      _Pragma("unroll")                                                    \
      for (int ni = 0; ni < 4; ++ni)                                       \
        acc[mi][ni] = __builtin_amdgcn_mfma_f32_16x16x32_bf16(a_[mi], bb_[ni], acc[mi][ni], 0, 0, 0); \
    __builtin_amdgcn_s_setprio(0);                                         \
  } while (0)

#define WAIT6 asm volatile("s_waitcnt vmcnt(6)" ::: "memory")
#define WAIT0 asm volatile("s_waitcnt vmcnt(0)" ::: "memory")
#define BARR  do { __builtin_amdgcn_s_barrier(); asm volatile("" ::: "memory"); } while (0)

  STG(0, 0); STG(1, 1);
  for (int j = 0; j < 42; ++j) {
    const int h = 3 * j;
    WAIT6; BARR; STG(2, h + 2); COMP(0);
    WAIT6; BARR; STG(0, h + 3); COMP(1);
    WAIT6; BARR; STG(1, h + 4); COMP(2);
  }
  WAIT6; BARR; COMP(0);   // h = 126
  WAIT0; BARR; COMP(1);   // h = 127

#undef STG
#undef COMP
#undef WAIT6
#undef WAIT0
#undef BARR

  // ---- epilogue ----
  if (EPI == 0) {
#pragma unroll
    for (int ni = 0; ni < 4; ++ni) {
      const int ncol = n0 + wc * 64 + ni * 16 + c;
      const int which = ncol >> 12;
      const int h = (ncol >> 7) & 31;
      const int dcl = ncol & 127;
      short* dst = (which == 0) ? Qb : ((which == 1) ? Kb : Vb);
      const float bv = bias[ncol];
#pragma unroll
      for (int mi = 0; mi < 8; ++mi)
#pragma unroll
        for (int jj = 0; jj < 4; ++jj) {
          const int row = m0 + wr * 128 + mi * 16 + g * 4 + jj;
          dst[((size_t)h * S_LEN + row) * HD + dcl] = f2bf(acc[mi][ni][jj] + bv);
        }
    }
  } else {
#pragma unroll
    for (int ni = 0; ni < 4; ++ni) {
      const int ncol = n0 + wc * 64 + ni * 16 + c;
#pragma unroll
      for (int mi = 0; mi < 8; ++mi)
#pragma unroll
        for (int jj = 0; jj < 4; ++jj) {
          const int row = m0 + wr * 128 + mi * 16 + g * 4 + jj;
          Cout[(size_t)row * HID + ncol] = acc[mi][ni][jj];
        }
    }
  }
}

// ============ fallback GEMM (reg-staged) ============
template<int EPI, int ABF16>
__global__ __launch_bounds__(256)
void gemm_kernel(const void* __restrict__ Av, const float* __restrict__ B,
                 const float* __restrict__ bias, const int N,
                 short* __restrict__ Qb, short* __restrict__ Kb, short* __restrict__ Vb,
                 float* __restrict__ Cout)
{
  __shared__ short As[128][40];
  __shared__ short Bs[128][40];
  const int m0 = blockIdx.x * 128;
  const int nb = blockIdx.y * 128;
  const int t  = threadIdx.x;
  const int w = t >> 6, lane = t & 63, c = lane & 15, g = lane >> 4;
  const int wm = (w >> 1) * 64, wn = (w & 1) * 64;

  f32x4 acc[4][4];
#pragma unroll
  for (int i = 0; i < 4; i++)
#pragma unroll
    for (int j = 0; j < 4; j++) acc[i][j] = (f32x4){0.f, 0.f, 0.f, 0.f};

  const int ar = t >> 3;
  const int ac = (t & 7) * 4;
  const int bn = t & 127;
  const int bkq = (t >> 7) * 16;

  for (int k0 = 0; k0 < KD; k0 += 32) {
#pragma unroll
    for (int rr = 0; rr < 4; rr++) {
      const int row = rr * 32 + ar;
      if (ABF16) {
        *(s16x4*)&As[row][ac] =
          *(const s16x4*)((const short*)Av + (size_t)(m0 + row) * KD + k0 + ac);
      } else {
        f32x4 v = *(const f32x4*)((const float*)Av + (size_t)(m0 + row) * KD + k0 + ac);
        s16x4 pk;
        pk[0] = f2bf(v[0]); pk[1] = f2bf(v[1]); pk[2] = f2bf(v[2]); pk[3] = f2bf(v[3]);
        *(s16x4*)&As[row][ac] = pk;
      }
    }
    const float* pB = B + (size_t)(k0 + bkq) * N + nb + bn;
    s16x8 b0, b1;
#pragma unroll
    for (int i = 0; i < 8; i++) b0[i] = f2bf(pB[(size_t)i * N]);
#pragma unroll
    for (int i = 0; i < 8; i++) b1[i] = f2bf(pB[(size_t)(i + 8) * N]);
    *(s16x8*)&Bs[bn][bkq]     = b0;
    *(s16x8*)&Bs[bn][bkq + 8] = b1;
    __syncthreads();
    s16x8 af[4], bfr[4];
#pragma unroll
    for (int i = 0; i < 4; i++) af[i]  = *(const s16x8*)&As[wm + i * 16 + c][g * 8];
#pragma unroll
    for (int i = 0; i < 4; i++) bfr[i] = *(const s16x8*)&Bs[wn + i * 16 + c][g * 8];
#pragma unroll
    for (int mi = 0; mi < 4; mi++)
#pragma unroll
      for (int ni = 0; ni < 4; ni++)
        acc[mi][ni] = __builtin_amdgcn_mfma_f32_16x16x32_bf16(af[mi], bfr[ni], acc[mi][ni], 0, 0, 0);
    __syncthreads();
  }

  if (EPI == 0) {
    const int which = nb >> 12;
    const int h = (nb & 4095) >> 7;
    short* dst = (which == 0) ? Qb : ((which == 1) ? Kb : Vb);
#pragma unroll
    for (int ni = 0; ni < 4; ni++) {
      const int d = wn + ni * 16 + c;
      const float bv = bias[nb + d];
#pragma unroll
      for (int mi = 0; mi < 4; mi++)
#pragma unroll
        for (int j = 0; j < 4; j++) {
          const int row = m0 + wm + mi * 16 + g * 4 + j;
          dst[((size_t)h * S_LEN + row) * HD + d] = f2bf(acc[mi][ni][j] + bv);
        }
    }
  } else {
#pragma unroll
    for (int ni = 0; ni < 4; ni++) {
      const int n = nb + wn + ni * 16 + c;
#pragma unroll
      for (int mi = 0; mi < 4; mi++)
#pragma unroll
        for (int j = 0; j < 4; j++) {
          const int row = m0 + wm + mi * 16 + g * 4 + j;
          Cout[(size_t)row * N + n] = acc[mi][ni][j];
        }
    }
  }
}

// ============ RoPE ============
__global__ void rope_kernel(const int* __restrict__ positions,
                            short* __restrict__ Qb, short* __restrict__ Kb)
{
  const int s = blockIdx.x;
  const int h = blockIdx.y * 4 + threadIdx.y;
  const int d = threadIdx.x;
  const float pos = (float)positions[s];
  const float inv_freq = exp2f(-(float)d * 0.20762050593046014f);
  const float ang = pos * inv_freq;
  float sn, cs;
  sincosf(ang, &sn, &cs);
  const size_t base = ((size_t)h * S_LEN + s) * HD + d;
  const float scale = 0.08838834764831845f;
  float x1 = bf2f(Qb[base]), x2 = bf2f(Qb[base + 64]);
  Qb[base]      = f2bf((x1 * cs - x2 * sn) * scale);
  Qb[base + 64] = f2bf((x2 * cs + x1 * sn) * scale);
  x1 = bf2f(Kb[base]); x2 = bf2f(Kb[base + 64]);
  Kb[base]      = f2bf(x1 * cs - x2 * sn);
  Kb[base + 64] = f2bf(x2 * cs + x1 * sn);
}

// ============ V -> Vt [NH][HD][S] ============
__global__ __launch_bounds__(256)
void vtrans_kernel(const short* __restrict__ V, short* __restrict__ Vt)
{
  __shared__ short tile[64][72];
  const int h = blockIdx.z;
  const int s0 = blockIdx.x * 64;
  const int d0 = blockIdx.y * 64;
  const int tx = threadIdx.x & 63, ty = threadIdx.x >> 6;
  for (int r = ty; r < 64; r += 4)
    tile[r][tx] = V[((size_t)h * S_LEN + s0 + r) * HD + d0 + tx];
  __syncthreads();
  for (int r = ty; r < 64; r += 4)
    Vt[((size_t)h * HD + d0 + r) * S_LEN + s0 + tx] = tile[tx][r];
}

// ============ causal flash attention (LDS-staged K/V, double-buffered) ============
__global__ __launch_bounds__(512)
void attn_kernel(const short* __restrict__ Q, const short* __restrict__ Kg,
                 const short* __restrict__ Vtg, short* __restrict__ attn_out)
{
  __shared__ short Ks[2][32][136];
  __shared__ short Vs[2][128][40];
  __shared__ short Plds[8][16][40];
  const int h = blockIdx.y;
  const int q0 = blockIdx.x * 128;
  const int t = threadIdx.x;
  const int w = t >> 6, lane = t & 63, c = lane & 15, g = lane >> 4;
  const short* Qh = Q   + (size_t)h * S_LEN * HD;
  const short* Kh = Kg  + (size_t)h * S_LEN * HD;
  const short* Vh = Vtg + (size_t)h * HD * S_LEN;

  const int krow = t >> 4, kc16 = t & 15;
  const int vrow = t >> 2, vc16 = t & 3;

  const int qrow = q0 + w * 16 + c;
  s16x8 qf[4];
#pragma unroll
  for (int di = 0; di < 4; di++)
    qf[di] = *(const s16x8*)&Qh[(size_t)qrow * HD + di * 32 + g * 8];

  f32x4 o[8];
#pragma unroll
  for (int dt = 0; dt < 8; dt++) o[dt] = (f32x4){0.f, 0.f, 0.f, 0.f};
  float m_r[4], l_r[4];
#pragma unroll
  for (int j = 0; j < 4; j++) { m_r[j] = -3.0e38f; l_r[j] = 0.f; }

  const int nt = q0 / 32 + 4;

  {
    s16x8 gK = *(const s16x8*)&Kh[(size_t)krow * HD + kc16 * 8];
    s16x8 gV = *(const s16x8*)&Vh[(size_t)vrow * S_LEN + vc16 * 8];
    *(s16x8*)&Ks[0][krow][kc16 * 8] = gK;
    *(s16x8*)&Vs[0][vrow][vc16 * 8] = gV;
  }
  __syncthreads();

  for (int kt = 0; kt < nt; kt++) {
    const int cur = kt & 1;
    const int kb = kt * 32;
    s16x8 gK, gV;
    if (kt + 1 < nt) {
      gK = *(const s16x8*)&Kh[(size_t)(kb + 32 + krow) * HD + kc16 * 8];
      gV = *(const s16x8*)&Vh[(size_t)vrow * S_LEN + kb + 32 + vc16 * 8];
    }
    f32x4 s0 = (f32x4){0.f, 0.f, 0.f, 0.f}, s1 = (f32x4){0.f, 0.f, 0.f, 0.f};
#pragma unroll
    for (int di = 0; di < 4; di++) {
      s16x8 kf0 = *(const s16x8*)&Ks[cur][c][di * 32 + g * 8];
      s16x8 kf1 = *(const s16x8*)&Ks[cur][16 + c][di * 32 + g * 8];
      s0 = __builtin_amdgcn_mfma_f32_16x16x32_bf16(qf[di], kf0, s0, 0, 0, 0);
      s1 = __builtin_amdgcn_mfma_f32_16x16x32_bf16(qf[di], kf1, s1, 0, 0, 0);
    }
    float p0[4], p1[4], alpha[4];
#pragma unroll
    for (int j = 0; j < 4; j++) {
      const int qg = q0 + w * 16 + g * 4 + j;
      const float v0 = (kb + c      <= qg) ? s0[j] : -__builtin_inff();
      const float v1 = (kb + 16 + c <= qg) ? s1[j] : -__builtin_inff();
      float mx = fmaxf(v0, v1);
#pragma unroll
      for (int off = 1; off < 16; off <<= 1) mx = fmaxf(mx, __shfl_xor(mx, off, 64));
      const float mn = fmaxf(m_r[j], mx);
      alpha[j] = __expf(m_r[j] - mn);
      p0[j] = __expf(v0 - mn);
      p1[j] = __expf(v1 - mn);
      float rs = p0[j] + p1[j];
#pragma unroll
      for (int off = 1; off < 16; off <<= 1) rs += __shfl_xor(rs, off, 64);
      l_r[j] = l_r[j] * alpha[j] + rs;
      m_r[j] = mn;
    }
#pragma unroll
    for (int dt = 0; dt < 8; dt++)
#pragma unroll
      for (int j = 0; j < 4; j++) o[dt][j] *= alpha[j];
#pragma unroll
    for (int j = 0; j < 4; j++) {
      Plds[w][g * 4 + j][c]      = f2bf(p0[j]);
      Plds[w][g * 4 + j][16 + c] = f2bf(p1[j]);
    }
    const s16x8 pa = *(const s16x8*)&Plds[w][c][g * 8];
#pragma unroll
    for (int dt = 0; dt < 8; dt++) {
      s16x8 vf = *(const s16x8*)&Vs[cur][dt * 16 + c][g * 8];
      o[dt] = __builtin_amdgcn_mfma_f32_16x16x32_bf16(pa, vf, o[dt], 0, 0, 0);
    }
    __syncthreads();
    if (kt + 1 < nt) {
      *(s16x8*)&Ks[cur ^ 1][krow][kc16 * 8] = gK;
      *(s16x8*)&Vs[cur ^ 1][vrow][vc16 * 8] = gV;
    }
    __syncthreads();
  }

  float inv_l[4];
#pragma unroll
  for (int j = 0; j < 4; j++) inv_l[j] = 1.0f / l_r[j];
#pragma unroll
  for (int dt = 0; dt < 8; dt++)
#pragma unroll
    for (int j = 0; j < 4; j++) {
      const int row = q0 + w * 16 + g * 4 + j;
      attn_out[(size_t)row * HID + h * HD + dt * 16 + c] = f2bf(o[dt][j] * inv_l[j]);
    }
}

extern "C" void kernel_launch(void* const* d_in, const int* in_sizes, int n_in,
                              void* d_out, int out_size, void* d_ws, size_t ws_size,
                              hipStream_t stream)
{
  const int*   positions = (const int*)d_in[0];
  const float* hidden    = (const float*)d_in[1];
  const float* w_qkv     = (const float*)d_in[2];
  const float* b_qkv     = (const float*)d_in[3];
  const float* w_o       = (const float*)d_in[4];
  float* out = (float*)d_out;

  char* ws = (char*)d_ws;
  const size_t MB = (size_t)1 << 20;

  if (ws_size >= 224 * MB) {
    short* Ah    = (short*)(ws);                 // 16 MB  bf16 [S][KD]
    short* Wqt   = (short*)(ws + 16 * MB);       // 96 MB  bf16 [3*HID][KD]
    short* Wot   = (short*)(ws + 112 * MB);      // 32 MB  bf16 [HID][KD]
    short* Qb    = (short*)(ws + 144 * MB);      // 16 MB
    short* Kb    = (short*)(ws + 160 * MB);      // 16 MB
    short* Vb    = (short*)(ws + 176 * MB);      // 16 MB
    short* Vt    = (short*)(ws + 192 * MB);      // 16 MB
    short* attnb = (short*)(ws + 208 * MB);      // 16 MB  bf16 [S][HID]

    cvt_kernel<<<4096, 256, 0, stream>>>(hidden, Ah);
    transcvt_kernel<<<dim3(KD / 64, 3 * HID / 64), 256, 0, stream>>>(w_qkv, Wqt, 3 * HID);
    transcvt_kernel<<<dim3(KD / 64, HID / 64), 256, 0, stream>>>(w_o, Wot, HID);
    gemm5_kernel<0><<<768, 256, 0, stream>>>(Ah, Wqt, b_qkv, Qb, Kb, Vb, nullptr);
    rope_kernel<<<dim3(S_LEN, NH / 4), dim3(64, 4), 0, stream>>>(positions, Qb, Kb);
    vtrans_kernel<<<dim3(S_LEN / 64, HD / 64, NH), 256, 0, stream>>>(Vb, Vt);
    attn_kernel<<<dim3(S_LEN / 128, NH), 512, 0, stream>>>(Qb, Kb, Vt, attnb);
    gemm5_kernel<1><<<256, 256, 0, stream>>>(attnb, Wot, nullptr,
                                             nullptr, nullptr, nullptr, out);
  } else {
    short* Qb    = (short*)(ws);
    short* Kb    = (short*)(ws + 16 * MB);
    short* Vb    = (short*)(ws + 32 * MB);
    short* Vt    = (short*)(ws + 48 * MB);
    short* attnb = (short*)(ws + 64 * MB);

    gemm_kernel<0, 0><<<dim3(16, 96), 256, 0, stream>>>(hidden, w_qkv, b_qkv, 3 * HID,
                                                        Qb, Kb, Vb, nullptr);
    rope_kernel<<<dim3(S_LEN, NH / 4), dim3(64, 4), 0, stream>>>(positions, Qb, Kb);
    vtrans_kernel<<<dim3(S_LEN / 64, HD / 64, NH), 256, 0, stream>>>(Vb, Vt);
    attn_kernel<<<dim3(S_LEN / 128, NH), 512, 0, stream>>>(Qb, Kb, Vt, attnb);
    gemm_kernel<1, 1><<<dim3(16, 32), 256, 0, stream>>>(attnb, w_o, nullptr, HID,
                                                        nullptr, nullptr, nullptr, out);
  }
}

// Round 7
// 485.272 us; speedup vs baseline: 2.3903x; 1.1644x over previous
//
#include <hip/hip_runtime.h>
#include <hip/hip_bf16.h>

#define S_LEN 2048
#define HID   4096
#define NH    32
#define HD    128
#define KD    4096

typedef __attribute__((ext_vector_type(4))) float f32x4;
typedef __attribute__((ext_vector_type(8))) short s16x8;
typedef __attribute__((ext_vector_type(4))) short s16x4;

#define AS1 __attribute__((address_space(1)))
#define AS3 __attribute__((address_space(3)))

__device__ __forceinline__ void gl_lds16(const void* g, void* l) {
  __builtin_amdgcn_global_load_lds((const AS1 void*)g, (AS3 void*)l, 16, 0, 0);
}

__device__ inline short f2bf(float f) {
  union { float f; unsigned u; } v; v.f = f;
  return (short)((v.u + 0x7fffu + ((v.u >> 16) & 1u)) >> 16);
}
__device__ inline float bf2f(short s) {
  union { unsigned u; float f; } v; v.u = ((unsigned)(unsigned short)s) << 16;
  return v.f;
}
__device__ inline unsigned packbf(float a, float b) {
  return (unsigned)(unsigned short)f2bf(a) | ((unsigned)(unsigned short)f2bf(b) << 16);
}

// ============ one-time converts ============
__global__ __launch_bounds__(256)
void cvt_kernel(const float* __restrict__ A, short* __restrict__ Ab) {
  const size_t i = ((size_t)blockIdx.x * 256 + threadIdx.x) * 8;
  f32x4 v0 = *(const f32x4*)&A[i];
  f32x4 v1 = *(const f32x4*)&A[i + 4];
  s16x8 r;
  r[0]=f2bf(v0[0]); r[1]=f2bf(v0[1]); r[2]=f2bf(v0[2]); r[3]=f2bf(v0[3]);
  r[4]=f2bf(v1[0]); r[5]=f2bf(v1[1]); r[6]=f2bf(v1[2]); r[7]=f2bf(v1[3]);
  *(s16x8*)&Ab[i] = r;
}

// W [KD][N] f32 -> Wt [N][KD] bf16
__global__ __launch_bounds__(256)
void transcvt_kernel(const float* __restrict__ W, short* __restrict__ Wt, const int N) {
  __shared__ float tile[64][65];
  const int k0 = blockIdx.x * 64, n0 = blockIdx.y * 64;
  const int t = threadIdx.x;
#pragma unroll
  for (int i = 0; i < 16; ++i) {
    const int e = i * 256 + t;
    const int k = e >> 6, n = e & 63;
    tile[n][k] = W[(size_t)(k0 + k) * N + n0 + n];
  }
  __syncthreads();
  const int nn = t >> 2, ks = (t & 3) * 16;
  s16x8 a, b;
#pragma unroll
  for (int i = 0; i < 8; i++) a[i] = f2bf(tile[nn][ks + i]);
#pragma unroll
  for (int i = 0; i < 8; i++) b[i] = f2bf(tile[nn][ks + 8 + i]);
  *(s16x8*)&Wt[(size_t)(n0 + nn) * KD + k0 + ks]     = a;
  *(s16x8*)&Wt[(size_t)(n0 + nn) * KD + k0 + ks + 8] = b;
}

// ============ gemm5: BM=256 BN=128, 4 waves (2Mx2N), wave-tile 128x64, ============
// 3-deep ring of K=32 half-tiles, counted vmcnt, XOR-swizzled LDS. (r6-proven)
template<int EPI>
__global__ __launch_bounds__(256, 2)
void gemm5_kernel(const short* __restrict__ A, const short* __restrict__ Bt,
                  const float* __restrict__ bias,
                  short* __restrict__ Qb, short* __restrict__ Kb, short* __restrict__ Vb,
                  float* __restrict__ Cout)
{
  __shared__ char sm[3][24576] __attribute__((aligned(128)));
  const int KD2 = KD * 2;
  const int bid = blockIdx.x;
  const int xcd = bid & 7, idx = bid >> 3;
  const int m0 = (idx & 7) * 256;
  const int n0 = (xcd * ((EPI == 0) ? 12 : 4) + (idx >> 3)) * 128;

  const int t = threadIdx.x, lane = t & 63, c = lane & 15, g = lane >> 4;
  const int w = t >> 6, wr = w >> 1, wc = w & 1;
  const int flip = ((c >> 1) & 7) << 4;
  const int laneA = wr * 8192 + ((c * 64 + g * 16) ^ flip);
  const int laneB = 16384 + wc * 4096 + ((c * 64 + g * 16) ^ flip);

  const char* srcA[4];
  const char* srcB[2];
#pragma unroll
  for (int j = 0; j < 4; ++j) {
    const int la = j * 4096 + t * 16;
    const int ls = la ^ ((la >> 3) & 0x70);
    srcA[j] = (const char*)A + (size_t)(m0 + (ls >> 6)) * KD2 + (ls & 63);
  }
#pragma unroll
  for (int j = 0; j < 2; ++j) {
    const int la = j * 4096 + t * 16;
    const int ls = la ^ ((la >> 3) & 0x70);
    srcB[j] = (const char*)Bt + (size_t)(n0 + (ls >> 6)) * KD2 + (ls & 63);
  }

  f32x4 acc[8][4];
#pragma unroll
  for (int i = 0; i < 8; i++)
#pragma unroll
    for (int j = 0; j < 4; j++) acc[i][j] = (f32x4){0.f, 0.f, 0.f, 0.f};

#define STG(S, H) do {                                        \
    const size_t ko_ = (size_t)(H) * 64;                      \
    gl_lds16(srcA[0] + ko_, sm[S] + t * 16);                  \
    gl_lds16(srcA[1] + ko_, sm[S] + 4096  + t * 16);          \
    gl_lds16(srcA[2] + ko_, sm[S] + 8192  + t * 16);          \
    gl_lds16(srcA[3] + ko_, sm[S] + 12288 + t * 16);          \
    gl_lds16(srcB[0] + ko_, sm[S] + 16384 + t * 16);          \
    gl_lds16(srcB[1] + ko_, sm[S] + 20480 + t * 16);          \
  } while (0)

#define COMP(S) do {                                                       \
    const char* b_ = sm[S];                                                \
    s16x8 a_[8], bb_[4];                                                   \
    _Pragma("unroll")                                                      \
    for (int mi = 0; mi < 8; ++mi) a_[mi] = *(const s16x8*)(b_ + laneA + mi * 1024); \
    _Pragma("unroll")                                                      \
    for (int ni = 0; ni < 4; ++ni) bb_[ni] = *(const s16x8*)(b_ + laneB + ni * 1024); \
    __builtin_amdgcn_s_setprio(1);                                         \
    _Pragma("unroll")                                                      \
    for (int mi = 0; mi < 8; ++mi)                                         \
      _Pragma("unroll")                                                    \
      for (int ni = 0; ni < 4; ++ni)                                       \
        acc[mi][ni] = __builtin_amdgcn_mfma_f32_16x16x32_bf16(a_[mi], bb_[ni], acc[mi][ni], 0, 0, 0); \
    __builtin_amdgcn_s_setprio(0);                                         \
  } while (0)

#define WAIT6 asm volatile("s_waitcnt vmcnt(6)" ::: "memory")
#define WAIT0 asm volatile("s_waitcnt vmcnt(0)" ::: "memory")
#define BARR  do { __builtin_amdgcn_s_barrier(); asm volatile("" ::: "memory"); } while (0)

  STG(0, 0); STG(1, 1);
  for (int j = 0; j < 42; ++j) {
    const int h = 3 * j;
    WAIT6; BARR; STG(2, h + 2); COMP(0);
    WAIT6; BARR; STG(0, h + 3); COMP(1);
    WAIT6; BARR; STG(1, h + 4); COMP(2);
  }
  WAIT6; BARR; COMP(0);
  WAIT0; BARR; COMP(1);

#undef STG
#undef COMP
#undef WAIT6
#undef WAIT0
#undef BARR

  if (EPI == 0) {
#pragma unroll
    for (int ni = 0; ni < 4; ++ni) {
      const int ncol = n0 + wc * 64 + ni * 16 + c;
      const int which = ncol >> 12;
      const int h = (ncol >> 7) & 31;
      const int dcl = ncol & 127;
      short* dst = (which == 0) ? Qb : ((which == 1) ? Kb : Vb);
      const float bv = bias[ncol];
#pragma unroll
      for (int mi = 0; mi < 8; ++mi)
#pragma unroll
        for (int jj = 0; jj < 4; ++jj) {
          const int row = m0 + wr * 128 + mi * 16 + g * 4 + jj;
          dst[((size_t)h * S_LEN + row) * HD + dcl] = f2bf(acc[mi][ni][jj] + bv);
        }
    }
  } else {
#pragma unroll
    for (int ni = 0; ni < 4; ++ni) {
      const int ncol = n0 + wc * 64 + ni * 16 + c;
#pragma unroll
      for (int mi = 0; mi < 8; ++mi)
#pragma unroll
        for (int jj = 0; jj < 4; ++jj) {
          const int row = m0 + wr * 128 + mi * 16 + g * 4 + jj;
          Cout[(size_t)row * HID + ncol] = acc[mi][ni][jj];
        }
    }
  }
}

// ============ fallback GEMM (reg-staged) ============
template<int EPI, int ABF16>
__global__ __launch_bounds__(256)
void gemm_kernel(const void* __restrict__ Av, const float* __restrict__ B,
                 const float* __restrict__ bias, const int N,
                 short* __restrict__ Qb, short* __restrict__ Kb, short* __restrict__ Vb,
                 float* __restrict__ Cout)
{
  __shared__ short As[128][40];
  __shared__ short Bs[128][40];
  const int m0 = blockIdx.x * 128;
  const int nb = blockIdx.y * 128;
  const int t  = threadIdx.x;
  const int w = t >> 6, lane = t & 63, c = lane & 15, g = lane >> 4;
  const int wm = (w >> 1) * 64, wn = (w & 1) * 64;

  f32x4 acc[4][4];
#pragma unroll
  for (int i = 0; i < 4; i++)
#pragma unroll
    for (int j = 0; j < 4; j++) acc[i][j] = (f32x4){0.f, 0.f, 0.f, 0.f};

  const int ar = t >> 3;
  const int ac = (t & 7) * 4;
  const int bn = t & 127;
  const int bkq = (t >> 7) * 16;

  for (int k0 = 0; k0 < KD; k0 += 32) {
#pragma unroll
    for (int rr = 0; rr < 4; rr++) {
      const int row = rr * 32 + ar;
      if (ABF16) {
        *(s16x4*)&As[row][ac] =
          *(const s16x4*)((const short*)Av + (size_t)(m0 + row) * KD + k0 + ac);
      } else {
        f32x4 v = *(const f32x4*)((const float*)Av + (size_t)(m0 + row) * KD + k0 + ac);
        s16x4 pk;
        pk[0] = f2bf(v[0]); pk[1] = f2bf(v[1]); pk[2] = f2bf(v[2]); pk[3] = f2bf(v[3]);
        *(s16x4*)&As[row][ac] = pk;
      }
    }
    const float* pB = B + (size_t)(k0 + bkq) * N + nb + bn;
    s16x8 b0, b1;
#pragma unroll
    for (int i = 0; i < 8; i++) b0[i] = f2bf(pB[(size_t)i * N]);
#pragma unroll
    for (int i = 0; i < 8; i++) b1[i] = f2bf(pB[(size_t)(i + 8) * N]);
    *(s16x8*)&Bs[bn][bkq]     = b0;
    *(s16x8*)&Bs[bn][bkq + 8] = b1;
    __syncthreads();
    s16x8 af[4], bfr[4];
#pragma unroll
    for (int i = 0; i < 4; i++) af[i]  = *(const s16x8*)&As[wm + i * 16 + c][g * 8];
#pragma unroll
    for (int i = 0; i < 4; i++) bfr[i] = *(const s16x8*)&Bs[wn + i * 16 + c][g * 8];
#pragma unroll
    for (int mi = 0; mi < 4; mi++)
#pragma unroll
      for (int ni = 0; ni < 4; ni++)
        acc[mi][ni] = __builtin_amdgcn_mfma_f32_16x16x32_bf16(af[mi], bfr[ni], acc[mi][ni], 0, 0, 0);
    __syncthreads();
  }

  if (EPI == 0) {
    const int which = nb >> 12;
    const int h = (nb & 4095) >> 7;
    short* dst = (which == 0) ? Qb : ((which == 1) ? Kb : Vb);
#pragma unroll
    for (int ni = 0; ni < 4; ni++) {
      const int d = wn + ni * 16 + c;
      const float bv = bias[nb + d];
#pragma unroll
      for (int mi = 0; mi < 4; mi++)
#pragma unroll
        for (int j = 0; j < 4; j++) {
          const int row = m0 + wm + mi * 16 + g * 4 + j;
          dst[((size_t)h * S_LEN + row) * HD + d] = f2bf(acc[mi][ni][j] + bv);
        }
    }
  } else {
#pragma unroll
    for (int ni = 0; ni < 4; ni++) {
      const int n = nb + wn + ni * 16 + c;
#pragma unroll
      for (int mi = 0; mi < 4; mi++)
#pragma unroll
        for (int j = 0; j < 4; j++) {
          const int row = m0 + wm + mi * 16 + g * 4 + j;
          Cout[(size_t)row * N + n] = acc[mi][ni][j];
        }
    }
  }
}

// ============ RoPE ============
__global__ void rope_kernel(const int* __restrict__ positions,
                            short* __restrict__ Qb, short* __restrict__ Kb)
{
  const int s = blockIdx.x;
  const int h = blockIdx.y * 4 + threadIdx.y;
  const int d = threadIdx.x;
  const float pos = (float)positions[s];
  const float inv_freq = exp2f(-(float)d * 0.20762050593046014f);
  const float ang = pos * inv_freq;
  float sn, cs;
  sincosf(ang, &sn, &cs);
  const size_t base = ((size_t)h * S_LEN + s) * HD + d;
  const float scale = 0.08838834764831845f;
  float x1 = bf2f(Qb[base]), x2 = bf2f(Qb[base + 64]);
  Qb[base]      = f2bf((x1 * cs - x2 * sn) * scale);
  Qb[base + 64] = f2bf((x2 * cs + x1 * sn) * scale);
  x1 = bf2f(Kb[base]); x2 = bf2f(Kb[base + 64]);
  Kb[base]      = f2bf(x1 * cs - x2 * sn);
  Kb[base + 64] = f2bf(x2 * cs + x1 * sn);
}

// ============ V -> Vt [NH][HD][S] ============
__global__ __launch_bounds__(256)
void vtrans_kernel(const short* __restrict__ V, short* __restrict__ Vt)
{
  __shared__ short tile[64][72];
  const int h = blockIdx.z;
  const int s0 = blockIdx.x * 64;
  const int d0 = blockIdx.y * 64;
  const int tx = threadIdx.x & 63, ty = threadIdx.x >> 6;
  for (int r = ty; r < 64; r += 4)
    tile[r][tx] = V[((size_t)h * S_LEN + s0 + r) * HD + d0 + tx];
  __syncthreads();
  for (int r = ty; r < 64; r += 4)
    Vt[((size_t)h * HD + d0 + r) * S_LEN + s0 + tx] = tile[tx][r];
}

// ============ causal flash attention v3: swapped QK^T, in-register P, KVBLK=64 ============
// grid (S/128, NH), 8 waves; wave w owns q rows [q0+16w,+16); lane c = q-row.
// K A-frag rows permuted so lane (c,g) owns k = {8g..8g+7} u {32+8g..+7} -> P feeds PV
// B-frag directly. K_lds XOR-swizzled (3 bits). T13 defer-max (THR=8).
__global__ __launch_bounds__(512)
void attn_kernel(const short* __restrict__ Q, const short* __restrict__ Kg,
                 const short* __restrict__ Vtg, short* __restrict__ attn_out)
{
  __shared__ short Ks[2][64][128];   // linear 256B rows + XOR swizzle
  __shared__ short Vs[2][128][72];   // [d][k], 144B rows (bank-spread pad)
  const int h = blockIdx.y;
  const int q0 = blockIdx.x * 128;
  const int t = threadIdx.x;
  const int w = t >> 6, lane = t & 63, c = lane & 15, g = lane >> 4;
  const short* Qh = Q   + (size_t)h * S_LEN * HD;
  const short* Kh = Kg  + (size_t)h * S_LEN * HD;
  const short* Vh = Vtg + (size_t)h * HD * S_LEN;

  // staging coords (512 threads)
  const int krow = t >> 4, kch = t & 15;     // K pass i: row i*32+krow, 16B chunk kch
  const int vrow = t >> 3, vch = t & 7;      // V pass i: row i*64+vrow, 16B chunk vch
  const int ksw = (kch ^ ((krow & 3) | ((krow >> 1) & 4))) * 16;  // swizzled K write slot

  // K frag read bases: rows rbase + {0,4,32,36}, slot (di*4+g)^sb
  const int rbase = (c >> 2) * 8 + (c & 3);
  const int sb = (rbase & 3) | ((rbase >> 1) & 4);
  int koff[4];
#pragma unroll
  for (int di = 0; di < 4; ++di) koff[di] = ((di * 4 + g) ^ sb) * 16;

  const int qg = q0 + w * 16 + c;
  s16x8 qf[4];
#pragma unroll
  for (int di = 0; di < 4; di++)
    qf[di] = *(const s16x8*)&Qh[(size_t)qg * HD + di * 32 + g * 8];

  f32x4 o[8];
#pragma unroll
  for (int dt = 0; dt < 8; dt++) o[dt] = (f32x4){0.f, 0.f, 0.f, 0.f};
  float m_r = -3.0e38f, l_r = 0.f;

  const int nt = q0 / 64 + 2;

  // prologue: stage tile 0 into buf 0
  {
#pragma unroll
    for (int i = 0; i < 2; ++i) {
      s16x8 gK = *(const s16x8*)&Kh[(size_t)(i * 32 + krow) * HD + kch * 8];
      s16x8 gV = *(const s16x8*)&Vh[(size_t)(i * 64 + vrow) * S_LEN + vch * 8];
      *(s16x8*)((char*)&Ks[0][0][0] + (i * 32 + krow) * 256 + ksw) = gK;
      *(s16x8*)&Vs[0][i * 64 + vrow][vch * 8] = gV;
    }
  }
  __syncthreads();

  for (int kt = 0; kt < nt; kt++) {
    const int cur = kt & 1;
    const int kb = kt * 64;
    s16x8 gK0, gK1, gV0, gV1;
    if (kt + 1 < nt) {
      gK0 = *(const s16x8*)&Kh[(size_t)(kb + 64 + krow) * HD + kch * 8];
      gK1 = *(const s16x8*)&Kh[(size_t)(kb + 96 + krow) * HD + kch * 8];
      gV0 = *(const s16x8*)&Vh[(size_t)vrow * S_LEN + kb + 64 + vch * 8];
      gV1 = *(const s16x8*)&Vh[(size_t)(64 + vrow) * S_LEN + kb + 64 + vch * 8];
    }
    // ---- QK^T (swapped: A=K rows, B=Q) ----
    f32x4 sA = (f32x4){0,0,0,0}, sB = (f32x4){0,0,0,0};
    f32x4 sC = (f32x4){0,0,0,0}, sD = (f32x4){0,0,0,0};
    const char* kb_ = (const char*)&Ks[cur][0][0] + rbase * 256;
#pragma unroll
    for (int di = 0; di < 4; ++di) {
      const char* p = kb_ + koff[di];
      s16x8 kA = *(const s16x8*)(p);
      s16x8 kB = *(const s16x8*)(p + 1024);
      s16x8 kC = *(const s16x8*)(p + 8192);
      s16x8 kD = *(const s16x8*)(p + 9216);
      sA = __builtin_amdgcn_mfma_f32_16x16x32_bf16(kA, qf[di], sA, 0, 0, 0);
      sB = __builtin_amdgcn_mfma_f32_16x16x32_bf16(kB, qf[di], sB, 0, 0, 0);
      sC = __builtin_amdgcn_mfma_f32_16x16x32_bf16(kC, qf[di], sC, 0, 0, 0);
      sD = __builtin_amdgcn_mfma_f32_16x16x32_bf16(kD, qf[di], sD, 0, 0, 0);
    }
    // ---- mask + in-register softmax (lane owns q-row qg, k = kb+{8g+j,8g+4+j,32+8g+j,32+8g+4+j}) ----
    float v[16];
#pragma unroll
    for (int j = 0; j < 4; ++j) {
      v[j]      = (kb + 8 * g + j      <= qg) ? sA[j] : -__builtin_inff();
      v[4 + j]  = (kb + 8 * g + 4 + j  <= qg) ? sB[j] : -__builtin_inff();
      v[8 + j]  = (kb + 32 + 8 * g + j     <= qg) ? sC[j] : -__builtin_inff();
      v[12 + j] = (kb + 32 + 8 * g + 4 + j <= qg) ? sD[j] : -__builtin_inff();
    }
    float mx = v[0];
#pragma unroll
    for (int i = 1; i < 16; ++i) mx = fmaxf(mx, v[i]);
    mx = fmaxf(mx, __shfl_xor(mx, 16, 64));
    mx = fmaxf(mx, __shfl_xor(mx, 32, 64));
    const float mn = fmaxf(m_r, mx);
    if (!__all(mn - m_r <= 8.0f)) {          // T13 defer-max
      const float al = __expf(m_r - mn);
      l_r *= al;
#pragma unroll
      for (int dt = 0; dt < 8; dt++)
#pragma unroll
        for (int j = 0; j < 4; j++) o[dt][j] *= al;
      m_r = mn;
    }
    float p[16];
    float rs = 0.f;
#pragma unroll
    for (int i = 0; i < 16; ++i) { p[i] = __expf(v[i] - m_r); rs += p[i]; }
    rs += __shfl_xor(rs, 16, 64);
    rs += __shfl_xor(rs, 32, 64);
    l_r += rs;
    // ---- pack P directly into PV B-frags (no cross-lane movement) ----
    union { s16x8 v8; unsigned u[4]; } pb0, pb1;
    pb0.u[0] = packbf(p[0], p[1]);   pb0.u[1] = packbf(p[2], p[3]);
    pb0.u[2] = packbf(p[4], p[5]);   pb0.u[3] = packbf(p[6], p[7]);
    pb1.u[0] = packbf(p[8], p[9]);   pb1.u[1] = packbf(p[10], p[11]);
    pb1.u[2] = packbf(p[12], p[13]); pb1.u[3] = packbf(p[14], p[15]);
    // ---- PV: O^T = V * P  (A=V rows=d, B=P cols=q-rows) ----
#pragma unroll
    for (int dt = 0; dt < 8; dt++) {
      s16x8 vf0 = *(const s16x8*)&Vs[cur][dt * 16 + c][g * 8];
      s16x8 vf1 = *(const s16x8*)&Vs[cur][dt * 16 + c][32 + g * 8];
      o[dt] = __builtin_amdgcn_mfma_f32_16x16x32_bf16(vf0, pb0.v8, o[dt], 0, 0, 0);
      o[dt] = __builtin_amdgcn_mfma_f32_16x16x32_bf16(vf1, pb1.v8, o[dt], 0, 0, 0);
    }
    __syncthreads();
    if (kt + 1 < nt) {
      *(s16x8*)((char*)&Ks[cur ^ 1][0][0] + krow * 256 + ksw)        = gK0;
      *(s16x8*)((char*)&Ks[cur ^ 1][0][0] + (32 + krow) * 256 + ksw) = gK1;
      *(s16x8*)&Vs[cur ^ 1][vrow][vch * 8]      = gV0;
      *(s16x8*)&Vs[cur ^ 1][64 + vrow][vch * 8] = gV1;
    }
    __syncthreads();
  }

  const float inv_l = 1.0f / l_r;
#pragma unroll
  for (int dt = 0; dt < 8; dt++) {
    s16x4 pk;
#pragma unroll
    for (int j = 0; j < 4; j++) pk[j] = f2bf(o[dt][j] * inv_l);
    *(s16x4*)&attn_out[(size_t)qg * HID + h * HD + dt * 16 + g * 4] = pk;
  }
}

extern "C" void kernel_launch(void* const* d_in, const int* in_sizes, int n_in,
                              void* d_out, int out_size, void* d_ws, size_t ws_size,
                              hipStream_t stream)
{
  const int*   positions = (const int*)d_in[0];
  const float* hidden    = (const float*)d_in[1];
  const float* w_qkv     = (const float*)d_in[2];
  const float* b_qkv     = (const float*)d_in[3];
  const float* w_o       = (const float*)d_in[4];
  float* out = (float*)d_out;

  char* ws = (char*)d_ws;
  const size_t MB = (size_t)1 << 20;

  if (ws_size >= 224 * MB) {
    short* Ah    = (short*)(ws);                 // 16 MB  bf16 [S][KD]
    short* Wqt   = (short*)(ws + 16 * MB);       // 96 MB  bf16 [3*HID][KD]
    short* Wot   = (short*)(ws + 112 * MB);      // 32 MB  bf16 [HID][KD]
    short* Qb    = (short*)(ws + 144 * MB);      // 16 MB
    short* Kb    = (short*)(ws + 160 * MB);      // 16 MB
    short* Vb    = (short*)(ws + 176 * MB);      // 16 MB
    short* Vt    = (short*)(ws + 192 * MB);      // 16 MB
    short* attnb = (short*)(ws + 208 * MB);      // 16 MB  bf16 [S][HID]

    cvt_kernel<<<4096, 256, 0, stream>>>(hidden, Ah);
    transcvt_kernel<<<dim3(KD / 64, 3 * HID / 64), 256, 0, stream>>>(w_qkv, Wqt, 3 * HID);
    transcvt_kernel<<<dim3(KD / 64, HID / 64), 256, 0, stream>>>(w_o, Wot, HID);
    gemm5_kernel<0><<<768, 256, 0, stream>>>(Ah, Wqt, b_qkv, Qb, Kb, Vb, nullptr);
    rope_kernel<<<dim3(S_LEN, NH / 4), dim3(64, 4), 0, stream>>>(positions, Qb, Kb);
    vtrans_kernel<<<dim3(S_LEN / 64, HD / 64, NH), 256, 0, stream>>>(Vb, Vt);
    attn_kernel<<<dim3(S_LEN / 128, NH), 512, 0, stream>>>(Qb, Kb, Vt, attnb);
    gemm5_kernel<1><<<256, 256, 0, stream>>>(attnb, Wot, nullptr,
                                             nullptr, nullptr, nullptr, out);
  } else {
    short* Qb    = (short*)(ws);
    short* Kb    = (short*)(ws + 16 * MB);
    short* Vb    = (short*)(ws + 32 * MB);
    short* Vt    = (short*)(ws + 48 * MB);
    short* attnb = (short*)(ws + 64 * MB);

    gemm_kernel<0, 0><<<dim3(16, 96), 256, 0, stream>>>(hidden, w_qkv, b_qkv, 3 * HID,
                                                        Qb, Kb, Vb, nullptr);
    rope_kernel<<<dim3(S_LEN, NH / 4), dim3(64, 4), 0, stream>>>(positions, Qb, Kb);
    vtrans_kernel<<<dim3(S_LEN / 64, HD / 64, NH), 256, 0, stream>>>(Vb, Vt);
    attn_kernel<<<dim3(S_LEN / 128, NH), 512, 0, stream>>>(Qb, Kb, Vt, attnb);
    gemm_kernel<1, 1><<<dim3(16, 32), 256, 0, stream>>>(attnb, w_o, nullptr, HID,
                                                        nullptr, nullptr, nullptr, out);
  }
}